// Round 3
// baseline (3873.112 us; speedup 1.0000x reference)
//
#include <hip/hip_runtime.h>
#include <hip/hip_bf16.h>

#define T_ 768
#define A_ 24
#define S_ 576
#define Q_ 32
#define K_ 128
#define C_ 128
#define H_ 4
#define DH_ 32
#define L_ 3
#define PAIR_ 16
#define PTC_ 384
#define FF_ 256
#define SQ_ (S_*Q_)
#define SK_ (S_*K_)

// ---------------- init: x = (gather(token_atoms) @ w_pos) * qm + qsc ----------------
__global__ void k_init_x(const int* __restrict__ a2q_idx, const int* __restrict__ a2q_mask,
                         const int* __restrict__ qmask, const float* __restrict__ ta_act,
                         const float* __restrict__ qsc, const float* __restrict__ w_pos,
                         float* __restrict__ x) {
    int i = blockIdx.x * blockDim.x + threadIdx.x;   // over SQ_*C_
    if (i >= SQ_ * C_) return;
    int r = i / C_, c = i % C_;
    float v = 0.f;
    if (a2q_mask[r]) {
        int idx = a2q_idx[r];
        float p0 = ta_act[idx*3+0], p1 = ta_act[idx*3+1], p2 = ta_act[idx*3+2];
        v = p0 * w_pos[c] + p1 * w_pos[C_+c] + p2 * w_pos[2*C_+c];
    }
    v *= (float)qmask[r];
    x[i] = v + qsc[i];
}

// ---------------- LayerNorm: xn = LN(x) * s + b, one row per block (128 thr) ----------------
__global__ void k_ln(const float* __restrict__ x, const float* __restrict__ s,
                     const float* __restrict__ b, float* __restrict__ xn) {
    int r = blockIdx.x;
    int c = threadIdx.x;
    __shared__ float red[C_];
    float v = x[(size_t)r*C_ + c];
    red[c] = v; __syncthreads();
    for (int off = 64; off > 0; off >>= 1) { if (c < off) red[c] += red[c+off]; __syncthreads(); }
    float mean = red[0] * (1.0f/C_);
    __syncthreads();
    float d = v - mean;
    red[c] = d*d; __syncthreads();
    for (int off = 64; off > 0; off >>= 1) { if (c < off) red[c] += red[c+off]; __syncthreads(); }
    float var = red[0] * (1.0f/C_);
    xn[(size_t)r*C_ + c] = d * rsqrtf(var + 1e-5f) * s[c] + b[c];
}

// ---------------- q projection: q[s,h,qq,d] = scale * xn[s,qq,:] @ wq[:, h, d] ----------------
__global__ __launch_bounds__(256) void k_qproj(const float* __restrict__ xn,
                                               const float* __restrict__ wq,
                                               float* __restrict__ qb) {
    __shared__ float w[C_*C_];      // 64 KB
    __shared__ float xrow[2][C_];
    for (int i = threadIdx.x; i < C_*C_; i += 256) w[i] = wq[i];
    __syncthreads();
    int rp = threadIdx.x >> 7, c = threadIdx.x & 127;
    const float scale = 0.17677669529663687f;  // 1/sqrt(32)
    for (int r0 = blockIdx.x*2; r0 < SQ_; r0 += gridDim.x*2) {
        int r = r0 + rp;
        __syncthreads();
        xrow[rp][c] = xn[(size_t)r*C_ + c];
        __syncthreads();
        float acc = 0.f;
        #pragma unroll 8
        for (int cc = 0; cc < C_; cc++) acc += xrow[rp][cc] * w[cc*C_ + c];
        int s = r / Q_, qq = r & (Q_-1);
        int h = c >> 5, dd = c & 31;
        qb[(((size_t)s*H_ + h)*Q_ + qq)*DH_ + dd] = acc * scale;
    }
}

// ------- fused keys gather + K/V projection: keys_act = gather(xn)+ksc; k=ka@wk; v=ka@wv -------
__global__ __launch_bounds__(256) void k_kv(const float* __restrict__ xn,
                                            const int* __restrict__ q2k_idx, const int* __restrict__ q2k_mask,
                                            const float* __restrict__ ksc,
                                            const float* __restrict__ wk, const float* __restrict__ wv,
                                            float* __restrict__ kb, float* __restrict__ vb) {
    __shared__ float wks[C_*C_];    // 64 KB
    __shared__ float wvs[C_*C_];    // 64 KB
    __shared__ float krow[2][C_];
    for (int i = threadIdx.x; i < C_*C_; i += 256) { wks[i] = wk[i]; wvs[i] = wv[i]; }
    __syncthreads();
    int rp = threadIdx.x >> 7, c = threadIdx.x & 127;
    for (int r0 = blockIdx.x*2; r0 < SK_; r0 += gridDim.x*2) {
        int r = r0 + rp;
        __syncthreads();
        {
            int idx = q2k_idx[r];
            float g = q2k_mask[r] ? xn[(size_t)idx*C_ + c] : 0.f;
            krow[rp][c] = g + ksc[(size_t)r*C_ + c];
        }
        __syncthreads();
        float ak = 0.f, av = 0.f;
        #pragma unroll 8
        for (int cc = 0; cc < C_; cc++) {
            float xv = krow[rp][cc];
            ak += xv * wks[cc*C_ + c];
            av += xv * wvs[cc*C_ + c];
        }
        int s = r / K_, kk = r & (K_-1);
        int h = c >> 5, dd = c & 31;
        size_t o = (((size_t)s*H_ + h)*K_ + kk)*DH_ + dd;
        kb[o] = ak; vb[o] = av;
    }
}

// ---------------- per-subset attention (all 4 heads), pair bias fused, x += out @ wo ----------------
__global__ __launch_bounds__(256) void k_attn(const float* __restrict__ qb, const float* __restrict__ kb,
                                              const float* __restrict__ vb, const float* __restrict__ pair,
                                              const int* __restrict__ kmask_g, const float* __restrict__ wpair,
                                              const float* __restrict__ wo, float* __restrict__ x) {
    __shared__ float qs[H_*Q_*33];      // q (padded 33); later reused flat as o[4096]
    __shared__ float kbuf[H_*K_*33];    // k (padded 33); later v
    __shared__ float lg[H_*Q_*129];     // logits rows padded to 129; later wo (16384)
    __shared__ float wp[PAIR_*H_];
    __shared__ float kmsk[K_];
    int s = blockIdx.x;
    int t = threadIdx.x;

    for (int e = t; e < H_*Q_*DH_; e += 256) {
        int row = e >> 5, d = e & 31;
        qs[row*33 + d] = qb[(size_t)s*H_*Q_*DH_ + e];
    }
    for (int e = t; e < H_*K_*DH_; e += 256) {
        int row = e >> 5, d = e & 31;
        kbuf[row*33 + d] = kb[(size_t)s*H_*K_*DH_ + e];
    }
    if (t < PAIR_*H_) wp[t] = wpair[t];
    if (t < K_) kmsk[t] = (float)kmask_g[s*K_ + t];
    __syncthreads();

    // logits[h, qq, kk] = q.k + pair_bias + mask
    for (int P = t; P < Q_*K_; P += 256) {
        int qq = P >> 7, kk = P & 127;
        const float* pa = pair + (((size_t)s*Q_ + qq)*K_ + kk)*PAIR_;
        float bias[H_] = {0.f, 0.f, 0.f, 0.f};
        #pragma unroll
        for (int p = 0; p < PAIR_; p++) {
            float pv = pa[p];
            #pragma unroll
            for (int h = 0; h < H_; h++) bias[h] += pv * wp[p*H_ + h];
        }
        float mterm = (kmsk[kk] - 1.0f) * 1e9f;
        #pragma unroll
        for (int h = 0; h < H_; h++) {
            float acc = 0.f;
            #pragma unroll
            for (int d = 0; d < DH_; d++) acc += qs[(h*Q_+qq)*33 + d] * kbuf[(h*K_+kk)*33 + d];
            lg[(h*Q_+qq)*129 + kk] = acc + bias[h] + mterm;
        }
    }
    __syncthreads();

    // softmax over kk: 128 rows, 2 threads/row
    {
        int row = t >> 1, half = t & 1;
        float* Lr = &lg[row*129];
        float mx = -1e30f;
        for (int j = half*64; j < half*64 + 64; j++) mx = fmaxf(mx, Lr[j]);
        mx = fmaxf(mx, __shfl_xor(mx, 1));
        float sum = 0.f;
        for (int j = half*64; j < half*64 + 64; j++) { float e = __expf(Lr[j]-mx); Lr[j] = e; sum += e; }
        sum += __shfl_xor(sum, 1);
        float inv = 1.0f / sum;
        for (int j = half*64; j < half*64 + 64; j++) Lr[j] *= inv;
    }
    __syncthreads();

    // load v over k's LDS
    for (int e = t; e < H_*K_*DH_; e += 256) {
        int row = e >> 5, d = e & 31;
        kbuf[row*33 + d] = vb[(size_t)s*H_*K_*DH_ + e];
    }
    __syncthreads();

    // o[h,qq,d] = attn @ v  (store flat into qs region: o index = (h*Q+qq)*DH + d)
    #pragma unroll
    for (int i = 0; i < (H_*Q_*DH_)/256; i++) {
        int O = t + 256*i;
        int d = O & 31, row = O >> 5;          // row = h*Q+qq
        int h = row >> 5;
        float acc = 0.f;
        #pragma unroll 4
        for (int kk = 0; kk < K_; kk++) acc += lg[row*129 + kk] * kbuf[(h*K_+kk)*33 + d];
        qs[O] = acc;
    }
    __syncthreads();

    // wo into lg region
    for (int e = t; e < C_*C_; e += 256) lg[e] = wo[e];
    __syncthreads();

    // x[s,qq,c] += sum_{h,d} o[h,qq,d] * wo[h*32+d, c]
    #pragma unroll
    for (int i = 0; i < (Q_*C_)/256; i++) {
        int O = t + 256*i;
        int c = O & 127, qq = O >> 7;
        float acc = 0.f;
        #pragma unroll 4
        for (int hd = 0; hd < H_*DH_; hd++) {
            // o flat index: (h*Q + qq)*DH + d  with h = hd>>5, d = hd&31
            acc += qs[(hd >> 5)*(Q_*DH_) + qq*DH_ + (hd & 31)] * lg[hd*C_ + c];
        }
        x[((size_t)s*Q_ + qq)*C_ + c] += acc;
    }
}

// ---------------- LN2 + FF1: ffh = relu(LN2(x) @ w1) ----------------
__global__ __launch_bounds__(256) void k_ln2ff1(const float* __restrict__ x, const float* __restrict__ s,
                                                const float* __restrict__ b, const float* __restrict__ w1,
                                                float* __restrict__ ffh) {
    __shared__ float w[C_*FF_];     // 128 KB
    __shared__ float xrow[C_];
    __shared__ float rr[C_];
    for (int i = threadIdx.x; i < C_*FF_; i += 256) w[i] = w1[i];
    __syncthreads();
    for (int r = blockIdx.x; r < SQ_; r += gridDim.x) {
        __syncthreads();
        float v = 0.f;
        if (threadIdx.x < C_) { v = x[(size_t)r*C_ + threadIdx.x]; rr[threadIdx.x] = v; }
        __syncthreads();
        for (int off = 64; off > 0; off >>= 1) { if (threadIdx.x < off) rr[threadIdx.x] += rr[threadIdx.x+off]; __syncthreads(); }
        float mean = rr[0] * (1.0f/C_);
        __syncthreads();
        float d = v - mean;
        if (threadIdx.x < C_) rr[threadIdx.x] = d*d;
        __syncthreads();
        for (int off = 64; off > 0; off >>= 1) { if (threadIdx.x < off) rr[threadIdx.x] += rr[threadIdx.x+off]; __syncthreads(); }
        float var = rr[0] * (1.0f/C_);
        __syncthreads();
        if (threadIdx.x < C_) xrow[threadIdx.x] = d * rsqrtf(var + 1e-5f) * s[threadIdx.x] + b[threadIdx.x];
        __syncthreads();
        float acc = 0.f;
        #pragma unroll 8
        for (int cc = 0; cc < C_; cc++) acc += xrow[cc] * w[cc*FF_ + threadIdx.x];
        ffh[(size_t)r*FF_ + threadIdx.x] = fmaxf(acc, 0.f);
    }
}

// ---------------- FF2: x += ffh @ w2 ----------------
__global__ __launch_bounds__(256) void k_ff2(const float* __restrict__ ffh, const float* __restrict__ w2,
                                             float* __restrict__ x) {
    __shared__ float w[FF_*C_];     // 128 KB
    __shared__ float hrow[2][FF_];
    for (int i = threadIdx.x; i < FF_*C_; i += 256) w[i] = w2[i];
    __syncthreads();
    int rp = threadIdx.x >> 7, c = threadIdx.x & 127;
    for (int r0 = blockIdx.x*2; r0 < SQ_; r0 += gridDim.x*2) {
        __syncthreads();
        for (int e = threadIdx.x; e < 2*FF_; e += 256) hrow[e >> 8][e & 255] = ffh[(size_t)r0*FF_ + e];
        __syncthreads();
        float acc = 0.f;
        #pragma unroll 8
        for (int f = 0; f < FF_; f++) acc += hrow[rp][f] * w[f*C_ + c];
        x[(size_t)(r0+rp)*C_ + c] += acc;
    }
}

// ---------------- final mask + write skip (f32 out) ----------------
__global__ void k_finalmask(float* __restrict__ x, const int* __restrict__ qmask,
                            float* __restrict__ out_skip) {
    int i = blockIdx.x * blockDim.x + threadIdx.x;
    if (i >= SQ_*C_) return;
    float v = x[i] * (float)qmask[i / C_];
    x[i] = v;
    out_skip[i] = v;
}

// ---------------- token aggregation: proj-on-the-fly + relu + masked mean (f32 out) ----------------
__global__ __launch_bounds__(384) void k_token(const float* __restrict__ x, const int* __restrict__ q2a_idx,
                                               const int* __restrict__ q2a_mask, const int* __restrict__ dmask,
                                               const float* __restrict__ w_aggr, float* __restrict__ out) {
    __shared__ float xs[A_][C_];
    __shared__ float am[A_];
    int tt = blockIdx.x;
    int t = threadIdx.x;
    for (int e = t; e < A_*C_; e += 384) {
        int a = e >> 7, c = e & 127;
        int idx = q2a_idx[tt*A_ + a];
        int gm  = q2a_mask[tt*A_ + a];
        xs[a][c] = gm ? x[(size_t)idx*C_ + c] : 0.f;
    }
    if (t < A_) am[t] = (float)dmask[tt*A_ + t];
    __syncthreads();
    float acc[A_];
    #pragma unroll
    for (int a = 0; a < A_; a++) acc[a] = 0.f;
    for (int c = 0; c < C_; c++) {
        float wv = w_aggr[c*PTC_ + t];
        #pragma unroll
        for (int a = 0; a < A_; a++) acc[a] += xs[a][c] * wv;
    }
    float denom = 1e-10f, num = 0.f;
    #pragma unroll
    for (int a = 0; a < A_; a++) { denom += am[a]; num += am[a] * fmaxf(acc[a], 0.f); }
    out[(size_t)tt*PTC_ + t] = num / denom;
}

extern "C" void kernel_launch(void* const* d_in, const int* in_sizes, int n_in,
                              void* d_out, int out_size, void* d_ws, size_t ws_size,
                              hipStream_t stream) {
    const int*   qmask    = (const int*)d_in[0];
    const int*   dmask    = (const int*)d_in[1];
    const int*   a2q_idx  = (const int*)d_in[2];
    const int*   a2q_mask = (const int*)d_in[3];
    const int*   q2k_idx  = (const int*)d_in[4];
    const int*   q2k_mask = (const int*)d_in[5];
    const int*   q2a_idx  = (const int*)d_in[6];
    const int*   q2a_mask = (const int*)d_in[7];
    const float* ta_act   = (const float*)d_in[8];
    const float* qsc      = (const float*)d_in[9];
    const float* pair     = (const float*)d_in[10];
    const int*   kmask    = (const int*)d_in[11];
    const float* ksc      = (const float*)d_in[12];
    const float* w_pos    = (const float*)d_in[13];
    const float* w_aggr   = (const float*)d_in[14];
    const float* ln1_s    = (const float*)d_in[15];
    const float* ln1_b    = (const float*)d_in[16];
    const float* wq       = (const float*)d_in[17];
    const float* wk       = (const float*)d_in[18];
    const float* wv       = (const float*)d_in[19];
    const float* wpair    = (const float*)d_in[20];
    const float* wo       = (const float*)d_in[21];
    const float* ln2_s    = (const float*)d_in[22];
    const float* ln2_b    = (const float*)d_in[23];
    const float* w1       = (const float*)d_in[24];
    const float* w2       = (const float*)d_in[25];
    float* out = (float*)d_out;

    float* ws = (float*)d_ws;
    float* x    = ws;
    float* xn   = x    + (size_t)SQ_*C_;
    float* qbuf = xn   + (size_t)SQ_*C_;
    float* kbuf = qbuf + (size_t)SQ_*C_;
    float* vbuf = kbuf + (size_t)SK_*C_;
    float* ffh  = kbuf;  // alias: ffh used after attention consumed k

    k_init_x<<<(SQ_*C_)/256, 256, 0, stream>>>(a2q_idx, a2q_mask, qmask, ta_act, qsc, w_pos, x);

    for (int l = 0; l < L_; l++) {
        k_ln<<<SQ_, 128, 0, stream>>>(x, ln1_s + l*C_, ln1_b + l*C_, xn);
        k_qproj<<<1024, 256, 0, stream>>>(xn, wq + (size_t)l*C_*C_, qbuf);
        k_kv<<<1024, 256, 0, stream>>>(xn, q2k_idx, q2k_mask, ksc,
                                       wk + (size_t)l*C_*C_, wv + (size_t)l*C_*C_, kbuf, vbuf);
        k_attn<<<S_, 256, 0, stream>>>(qbuf, kbuf, vbuf, pair, kmask,
                                       wpair + l*PAIR_*H_, wo + (size_t)l*C_*C_, x);
        k_ln2ff1<<<1024, 256, 0, stream>>>(x, ln2_s + l*C_, ln2_b + l*C_, w1 + (size_t)l*C_*FF_, ffh);
        k_ff2<<<1024, 256, 0, stream>>>(ffh, w2 + (size_t)l*FF_*C_, x);
    }

    k_finalmask<<<(SQ_*C_)/256, 256, 0, stream>>>(x, qmask, out + (size_t)T_*PTC_);
    k_token<<<T_, 384, 0, stream>>>(x, q2a_idx, q2a_mask, dmask, w_aggr, out);
}

// Round 4
// 1860.066 us; speedup vs baseline: 2.0822x; 2.0822x over previous
//
#include <hip/hip_runtime.h>
#include <hip/hip_bf16.h>

#define T_ 768
#define A_ 24
#define S_ 576
#define Q_ 32
#define K_ 128
#define C_ 128
#define H_ 4
#define DH_ 32
#define L_ 3
#define PAIR_ 16
#define PTC_ 384
#define FF_ 256
#define SQ_ (S_*Q_)
#define SK_ (S_*K_)

typedef __attribute__((ext_vector_type(8))) short bf16x8;
typedef __attribute__((ext_vector_type(4))) float f32x4;

#define MFMA(a,b,c) __builtin_amdgcn_mfma_f32_16x16x32_bf16(a,b,c,0,0,0)

__device__ inline unsigned short f2b(float f) {
    union { float f; unsigned u; } v; v.f = f;
    unsigned u = v.u;
    return (unsigned short)((u + 0x7FFFu + ((u >> 16) & 1u)) >> 16);
}

// stage weights w[K][N] (f32 row-major) -> LDS wT[n][k] bf16, XOR-swizzled
template<int KD, int ND>
__device__ inline void stage_wT(const float* __restrict__ w, unsigned short* lds) {
    for (int e = threadIdx.x; e < KD*ND; e += 256) {
        int k = e / ND, n = e % ND;                 // coalesced read over n
        int byte = ((n*KD + k)*2) ^ ((n & 7) << 4);
        *(unsigned short*)((char*)lds + byte) = f2b(w[e]);
    }
}

// stage TR contiguous rows of src (row stride KD f32) -> LDS bf16 [row][k] swizzled
template<int KD, int TR>
__device__ inline void stage_rows(const float* __restrict__ src, size_t r0, unsigned short* lds) {
    for (int e4 = threadIdx.x; e4 < TR*(KD/4); e4 += 256) {
        int row = e4 / (KD/4), c4 = e4 % (KD/4);
        float4 v = ((const float4*)src)[(r0 + row)*(KD/4) + c4];
        int byte = ((row*KD + c4*4)*2) ^ ((row & 7) << 4);
        unsigned short* p = (unsigned short*)((char*)lds + byte);
        p[0]=f2b(v.x); p[1]=f2b(v.y); p[2]=f2b(v.z); p[3]=f2b(v.w);
    }
}

// load one MFMA fragment (8 bf16 along k) from swizzled LDS tile with row-length KD
template<int KD>
__device__ inline bf16x8 ldfrag(const unsigned short* lds, int row, int k) {
    int byte = ((row*KD + k)*2) ^ ((row & 7) << 4);
    return *(const bf16x8*)((const char*)lds + byte);
}

// ---------------- init: x = (gather(token_atoms) @ w_pos) * qm + qsc ----------------
__global__ void k_init_x(const int* __restrict__ a2q_idx, const int* __restrict__ a2q_mask,
                         const int* __restrict__ qmask, const float* __restrict__ ta_act,
                         const float* __restrict__ qsc, const float* __restrict__ w_pos,
                         float* __restrict__ x) {
    int i = blockIdx.x * blockDim.x + threadIdx.x;   // over SQ_*C_
    if (i >= SQ_ * C_) return;
    int r = i / C_, c = i % C_;
    float v = 0.f;
    if (a2q_mask[r]) {
        int idx = a2q_idx[r];
        float p0 = ta_act[idx*3+0], p1 = ta_act[idx*3+1], p2 = ta_act[idx*3+2];
        v = p0 * w_pos[c] + p1 * w_pos[C_+c] + p2 * w_pos[2*C_+c];
    }
    v *= (float)qmask[r];
    x[i] = v + qsc[i];
}

// ---------------- LayerNorm: xn = LN(x) * s + b, one row per block (128 thr) ----------------
__global__ void k_ln(const float* __restrict__ x, const float* __restrict__ s,
                     const float* __restrict__ b, float* __restrict__ xn) {
    int r = blockIdx.x;
    int c = threadIdx.x;
    __shared__ float red[C_];
    float v = x[(size_t)r*C_ + c];
    red[c] = v; __syncthreads();
    for (int off = 64; off > 0; off >>= 1) { if (c < off) red[c] += red[c+off]; __syncthreads(); }
    float mean = red[0] * (1.0f/C_);
    __syncthreads();
    float d = v - mean;
    red[c] = d*d; __syncthreads();
    for (int off = 64; off > 0; off >>= 1) { if (c < off) red[c] += red[c+off]; __syncthreads(); }
    float var = red[0] * (1.0f/C_);
    xn[(size_t)r*C_ + c] = d * rsqrtf(var + 1e-5f) * s[c] + b[c];
}

// ---------------- q projection via MFMA: qb[s,h,qq,d] = scale * xn @ wq ----------------
__global__ __launch_bounds__(256) void k_qproj_m(const float* __restrict__ xn,
                                                 const float* __restrict__ wq,
                                                 float* __restrict__ qb) {
    __shared__ unsigned short wT[C_*C_];   // 32 KB
    __shared__ unsigned short at[64*C_];   // 16 KB
    stage_wT<C_, C_>(wq, wT);
    size_t r0 = (size_t)blockIdx.x * 64;
    __syncthreads();
    stage_rows<C_, 64>(xn, r0, at);
    __syncthreads();
    int t = threadIdx.x, wid = t>>6, lane = t&63, lr = lane&15, g = lane>>4;
    int mh = (wid&1)*32, nh = (wid>>1)*64;
    f32x4 acc[2][4] = {};
    #pragma unroll
    for (int ks = 0; ks < 4; ks++) {
        int ka = ks*32 + g*8;
        bf16x8 a0 = ldfrag<C_>(at, mh + lr, ka);
        bf16x8 a1 = ldfrag<C_>(at, mh + 16 + lr, ka);
        #pragma unroll
        for (int nt = 0; nt < 4; nt++) {
            bf16x8 b = ldfrag<C_>(wT, nh + nt*16 + lr, ka);
            acc[0][nt] = MFMA(a0, b, acc[0][nt]);
            acc[1][nt] = MFMA(a1, b, acc[1][nt]);
        }
    }
    const float scale = 0.17677669529663687f;  // 1/sqrt(32)
    #pragma unroll
    for (int mt = 0; mt < 2; mt++)
    #pragma unroll
    for (int nt = 0; nt < 4; nt++)
    #pragma unroll
    for (int r = 0; r < 4; r++) {
        int row = (int)r0 + mh + mt*16 + g*4 + r;
        int col = nh + nt*16 + lr;
        int s = row>>5, qq = row&31, h = col>>5, dd = col&31;
        qb[(((size_t)s*H_ + h)*Q_ + qq)*DH_ + dd] = acc[mt][nt][r] * scale;
    }
}

// ------- fused keys gather + K/V projection via MFMA -------
__global__ __launch_bounds__(256) void k_kv_m(const float* __restrict__ xn,
    const int* __restrict__ q2k_idx, const int* __restrict__ q2k_mask,
    const float* __restrict__ ksc,
    const float* __restrict__ wk, const float* __restrict__ wv,
    float* __restrict__ kb, float* __restrict__ vb) {
    __shared__ unsigned short wkT[C_*C_];  // 32 KB
    __shared__ unsigned short wvT[C_*C_];  // 32 KB
    __shared__ unsigned short at[64*C_];   // 16 KB
    stage_wT<C_, C_>(wk, wkT);
    stage_wT<C_, C_>(wv, wvT);
    int t = threadIdx.x, wid = t>>6, lane = t&63, lr = lane&15, g = lane>>4;
    int mh = (wid&1)*32, nh = (wid>>1)*64;
    for (int tile = blockIdx.x; tile < SK_/64; tile += gridDim.x) {
        int r0 = tile*64;
        __syncthreads();
        // gather + add ksc, stage bf16 swizzled
        for (int e4 = t; e4 < 64*(C_/4); e4 += 256) {
            int row = e4 >> 5, c4 = e4 & 31;
            int gr = r0 + row;
            float4 v;
            if (q2k_mask[gr]) v = ((const float4*)xn)[(size_t)q2k_idx[gr]*(C_/4) + c4];
            else              v = make_float4(0.f, 0.f, 0.f, 0.f);
            float4 kc = ((const float4*)ksc)[(size_t)gr*(C_/4) + c4];
            v.x += kc.x; v.y += kc.y; v.z += kc.z; v.w += kc.w;
            int byte = ((row*C_ + c4*4)*2) ^ ((row & 7) << 4);
            unsigned short* p = (unsigned short*)((char*)at + byte);
            p[0]=f2b(v.x); p[1]=f2b(v.y); p[2]=f2b(v.z); p[3]=f2b(v.w);
        }
        __syncthreads();
        f32x4 acc[2][4][2] = {};
        #pragma unroll
        for (int ks = 0; ks < 4; ks++) {
            int ka = ks*32 + g*8;
            bf16x8 a0 = ldfrag<C_>(at, mh + lr, ka);
            bf16x8 a1 = ldfrag<C_>(at, mh + 16 + lr, ka);
            #pragma unroll
            for (int nt = 0; nt < 4; nt++) {
                bf16x8 bk = ldfrag<C_>(wkT, nh + nt*16 + lr, ka);
                bf16x8 bv = ldfrag<C_>(wvT, nh + nt*16 + lr, ka);
                acc[0][nt][0] = MFMA(a0, bk, acc[0][nt][0]);
                acc[1][nt][0] = MFMA(a1, bk, acc[1][nt][0]);
                acc[0][nt][1] = MFMA(a0, bv, acc[0][nt][1]);
                acc[1][nt][1] = MFMA(a1, bv, acc[1][nt][1]);
            }
        }
        #pragma unroll
        for (int mt = 0; mt < 2; mt++)
        #pragma unroll
        for (int nt = 0; nt < 4; nt++)
        #pragma unroll
        for (int r = 0; r < 4; r++) {
            int row = r0 + mh + mt*16 + g*4 + r;
            int col = nh + nt*16 + lr;
            int s = row>>7, kk = row&127, h = col>>5, dd = col&31;
            size_t o = (((size_t)s*H_ + h)*K_ + kk)*DH_ + dd;
            kb[o] = acc[mt][nt][0][r];
            vb[o] = acc[mt][nt][1][r];
        }
    }
}

// ---------------- per-subset attention (fp32, unchanged) ----------------
__global__ __launch_bounds__(256) void k_attn(const float* __restrict__ qb, const float* __restrict__ kb,
                                              const float* __restrict__ vb, const float* __restrict__ pair,
                                              const int* __restrict__ kmask_g, const float* __restrict__ wpair,
                                              const float* __restrict__ wo, float* __restrict__ x) {
    __shared__ float qs[H_*Q_*33];      // q (padded 33); later reused flat as o[4096]
    __shared__ float kbuf[H_*K_*33];    // k (padded 33); later v
    __shared__ float lg[H_*Q_*129];     // logits rows padded to 129; later wo (16384)
    __shared__ float wp[PAIR_*H_];
    __shared__ float kmsk[K_];
    int s = blockIdx.x;
    int t = threadIdx.x;

    for (int e = t; e < H_*Q_*DH_; e += 256) {
        int row = e >> 5, d = e & 31;
        qs[row*33 + d] = qb[(size_t)s*H_*Q_*DH_ + e];
    }
    for (int e = t; e < H_*K_*DH_; e += 256) {
        int row = e >> 5, d = e & 31;
        kbuf[row*33 + d] = kb[(size_t)s*H_*K_*DH_ + e];
    }
    if (t < PAIR_*H_) wp[t] = wpair[t];
    if (t < K_) kmsk[t] = (float)kmask_g[s*K_ + t];
    __syncthreads();

    for (int P = t; P < Q_*K_; P += 256) {
        int qq = P >> 7, kk = P & 127;
        const float* pa = pair + (((size_t)s*Q_ + qq)*K_ + kk)*PAIR_;
        float bias[H_] = {0.f, 0.f, 0.f, 0.f};
        #pragma unroll
        for (int p = 0; p < PAIR_; p++) {
            float pv = pa[p];
            #pragma unroll
            for (int h = 0; h < H_; h++) bias[h] += pv * wp[p*H_ + h];
        }
        float mterm = (kmsk[kk] - 1.0f) * 1e9f;
        #pragma unroll
        for (int h = 0; h < H_; h++) {
            float acc = 0.f;
            #pragma unroll
            for (int d = 0; d < DH_; d++) acc += qs[(h*Q_+qq)*33 + d] * kbuf[(h*K_+kk)*33 + d];
            lg[(h*Q_+qq)*129 + kk] = acc + bias[h] + mterm;
        }
    }
    __syncthreads();

    {
        int row = t >> 1, half = t & 1;
        float* Lr = &lg[row*129];
        float mx = -1e30f;
        for (int j = half*64; j < half*64 + 64; j++) mx = fmaxf(mx, Lr[j]);
        mx = fmaxf(mx, __shfl_xor(mx, 1));
        float sum = 0.f;
        for (int j = half*64; j < half*64 + 64; j++) { float e = __expf(Lr[j]-mx); Lr[j] = e; sum += e; }
        sum += __shfl_xor(sum, 1);
        float inv = 1.0f / sum;
        for (int j = half*64; j < half*64 + 64; j++) Lr[j] *= inv;
    }
    __syncthreads();

    for (int e = t; e < H_*K_*DH_; e += 256) {
        int row = e >> 5, d = e & 31;
        kbuf[row*33 + d] = vb[(size_t)s*H_*K_*DH_ + e];
    }
    __syncthreads();

    #pragma unroll
    for (int i = 0; i < (H_*Q_*DH_)/256; i++) {
        int O = t + 256*i;
        int d = O & 31, row = O >> 5;          // row = h*Q+qq
        int h = row >> 5;
        float acc = 0.f;
        #pragma unroll 4
        for (int kk = 0; kk < K_; kk++) acc += lg[row*129 + kk] * kbuf[(h*K_+kk)*33 + d];
        qs[O] = acc;
    }
    __syncthreads();

    for (int e = t; e < C_*C_; e += 256) lg[e] = wo[e];
    __syncthreads();

    #pragma unroll
    for (int i = 0; i < (Q_*C_)/256; i++) {
        int O = t + 256*i;
        int c = O & 127, qq = O >> 7;
        float acc = 0.f;
        #pragma unroll 4
        for (int hd = 0; hd < H_*DH_; hd++) {
            acc += qs[(hd >> 5)*(Q_*DH_) + qq*DH_ + (hd & 31)] * lg[hd*C_ + c];
        }
        x[((size_t)s*Q_ + qq)*C_ + c] += acc;
    }
}

// ---------------- FF1 via MFMA: ffh = relu(xn2 @ w1) ----------------
__global__ __launch_bounds__(256) void k_ff1_m(const float* __restrict__ xn,
                                               const float* __restrict__ w1,
                                               float* __restrict__ ffh) {
    __shared__ unsigned short wT[C_*FF_];  // [n=256][k=128] 64 KB
    __shared__ unsigned short at[64*C_];   // 16 KB
    stage_wT<C_, FF_>(w1, wT);
    size_t r0 = (size_t)blockIdx.x * 64;
    __syncthreads();
    stage_rows<C_, 64>(xn, r0, at);
    __syncthreads();
    int t = threadIdx.x, wid = t>>6, lane = t&63, lr = lane&15, g = lane>>4;
    int mh = (wid&1)*32, nh = (wid>>1)*128;
    f32x4 acc[2][8] = {};
    #pragma unroll
    for (int ks = 0; ks < 4; ks++) {
        int ka = ks*32 + g*8;
        bf16x8 a0 = ldfrag<C_>(at, mh + lr, ka);
        bf16x8 a1 = ldfrag<C_>(at, mh + 16 + lr, ka);
        #pragma unroll
        for (int nt = 0; nt < 8; nt++) {
            bf16x8 b = ldfrag<C_>(wT, nh + nt*16 + lr, ka);
            acc[0][nt] = MFMA(a0, b, acc[0][nt]);
            acc[1][nt] = MFMA(a1, b, acc[1][nt]);
        }
    }
    #pragma unroll
    for (int mt = 0; mt < 2; mt++)
    #pragma unroll
    for (int nt = 0; nt < 8; nt++)
    #pragma unroll
    for (int r = 0; r < 4; r++) {
        int row = (int)r0 + mh + mt*16 + g*4 + r;
        int col = nh + nt*16 + lr;
        ffh[(size_t)row*FF_ + col] = fmaxf(acc[mt][nt][r], 0.f);
    }
}

// ---------------- FF2 via MFMA: x += ffh @ w2 ----------------
__global__ __launch_bounds__(256) void k_ff2_m(const float* __restrict__ ffh,
                                               const float* __restrict__ w2,
                                               float* __restrict__ x) {
    __shared__ unsigned short wT[FF_*C_];  // [n=128][k=256] 64 KB
    __shared__ unsigned short at[32*FF_];  // 16 KB
    stage_wT<FF_, C_>(w2, wT);
    size_t r0 = (size_t)blockIdx.x * 32;
    __syncthreads();
    stage_rows<FF_, 32>(ffh, r0, at);
    __syncthreads();
    int t = threadIdx.x, wid = t>>6, lane = t&63, lr = lane&15, g = lane>>4;
    int nq = wid*32;
    f32x4 acc[2][2] = {};
    #pragma unroll
    for (int ks = 0; ks < 8; ks++) {
        int ka = ks*32 + g*8;
        bf16x8 a0 = ldfrag<FF_>(at, lr, ka);
        bf16x8 a1 = ldfrag<FF_>(at, 16 + lr, ka);
        #pragma unroll
        for (int nt = 0; nt < 2; nt++) {
            bf16x8 b = ldfrag<FF_>(wT, nq + nt*16 + lr, ka);
            acc[0][nt] = MFMA(a0, b, acc[0][nt]);
            acc[1][nt] = MFMA(a1, b, acc[1][nt]);
        }
    }
    #pragma unroll
    for (int mt = 0; mt < 2; mt++)
    #pragma unroll
    for (int nt = 0; nt < 2; nt++)
    #pragma unroll
    for (int r = 0; r < 4; r++) {
        int row = (int)r0 + mt*16 + g*4 + r;
        int col = nq + nt*16 + lr;
        x[(size_t)row*C_ + col] += acc[mt][nt][r];
    }
}

// ---------------- final mask + write skip (f32 out) ----------------
__global__ void k_finalmask(float* __restrict__ x, const int* __restrict__ qmask,
                            float* __restrict__ out_skip) {
    int i = blockIdx.x * blockDim.x + threadIdx.x;
    if (i >= SQ_*C_) return;
    float v = x[i] * (float)qmask[i / C_];
    x[i] = v;
    out_skip[i] = v;
}

// ---------------- token aggregation (f32 out) ----------------
__global__ __launch_bounds__(384) void k_token(const float* __restrict__ x, const int* __restrict__ q2a_idx,
                                               const int* __restrict__ q2a_mask, const int* __restrict__ dmask,
                                               const float* __restrict__ w_aggr, float* __restrict__ out) {
    __shared__ float xs[A_][C_];
    __shared__ float am[A_];
    int tt = blockIdx.x;
    int t = threadIdx.x;
    for (int e = t; e < A_*C_; e += 384) {
        int a = e >> 7, c = e & 127;
        int idx = q2a_idx[tt*A_ + a];
        int gm  = q2a_mask[tt*A_ + a];
        xs[a][c] = gm ? x[(size_t)idx*C_ + c] : 0.f;
    }
    if (t < A_) am[t] = (float)dmask[tt*A_ + t];
    __syncthreads();
    float acc[A_];
    #pragma unroll
    for (int a = 0; a < A_; a++) acc[a] = 0.f;
    for (int c = 0; c < C_; c++) {
        float wv = w_aggr[c*PTC_ + t];
        #pragma unroll
        for (int a = 0; a < A_; a++) acc[a] += xs[a][c] * wv;
    }
    float denom = 1e-10f, num = 0.f;
    #pragma unroll
    for (int a = 0; a < A_; a++) { denom += am[a]; num += am[a] * fmaxf(acc[a], 0.f); }
    out[(size_t)tt*PTC_ + t] = num / denom;
}

extern "C" void kernel_launch(void* const* d_in, const int* in_sizes, int n_in,
                              void* d_out, int out_size, void* d_ws, size_t ws_size,
                              hipStream_t stream) {
    const int*   qmask    = (const int*)d_in[0];
    const int*   dmask    = (const int*)d_in[1];
    const int*   a2q_idx  = (const int*)d_in[2];
    const int*   a2q_mask = (const int*)d_in[3];
    const int*   q2k_idx  = (const int*)d_in[4];
    const int*   q2k_mask = (const int*)d_in[5];
    const int*   q2a_idx  = (const int*)d_in[6];
    const int*   q2a_mask = (const int*)d_in[7];
    const float* ta_act   = (const float*)d_in[8];
    const float* qsc      = (const float*)d_in[9];
    const float* pair     = (const float*)d_in[10];
    const int*   kmask    = (const int*)d_in[11];
    const float* ksc      = (const float*)d_in[12];
    const float* w_pos    = (const float*)d_in[13];
    const float* w_aggr   = (const float*)d_in[14];
    const float* ln1_s    = (const float*)d_in[15];
    const float* ln1_b    = (const float*)d_in[16];
    const float* wq       = (const float*)d_in[17];
    const float* wk       = (const float*)d_in[18];
    const float* wv       = (const float*)d_in[19];
    const float* wpair    = (const float*)d_in[20];
    const float* wo       = (const float*)d_in[21];
    const float* ln2_s    = (const float*)d_in[22];
    const float* ln2_b    = (const float*)d_in[23];
    const float* w1       = (const float*)d_in[24];
    const float* w2       = (const float*)d_in[25];
    float* out = (float*)d_out;

    float* ws = (float*)d_ws;
    float* x    = ws;
    float* xn   = x    + (size_t)SQ_*C_;   // also reused as LN2 output
    float* qbuf = xn   + (size_t)SQ_*C_;
    float* kbuf = qbuf + (size_t)SQ_*C_;
    float* vbuf = kbuf + (size_t)SK_*C_;
    float* ffh  = kbuf;  // alias: ffh used after attention consumed k

    k_init_x<<<(SQ_*C_)/256, 256, 0, stream>>>(a2q_idx, a2q_mask, qmask, ta_act, qsc, w_pos, x);

    for (int l = 0; l < L_; l++) {
        k_ln<<<SQ_, 128, 0, stream>>>(x, ln1_s + l*C_, ln1_b + l*C_, xn);
        k_qproj_m<<<SQ_/64, 256, 0, stream>>>(xn, wq + (size_t)l*C_*C_, qbuf);
        k_kv_m<<<576, 256, 0, stream>>>(xn, q2k_idx, q2k_mask, ksc,
                                        wk + (size_t)l*C_*C_, wv + (size_t)l*C_*C_, kbuf, vbuf);
        k_attn<<<S_, 256, 0, stream>>>(qbuf, kbuf, vbuf, pair, kmask,
                                       wpair + l*PAIR_*H_, wo + (size_t)l*C_*C_, x);
        k_ln<<<SQ_, 128, 0, stream>>>(x, ln2_s + l*C_, ln2_b + l*C_, xn);
        k_ff1_m<<<SQ_/64, 256, 0, stream>>>(xn, w1 + (size_t)l*C_*FF_, ffh);
        k_ff2_m<<<SQ_/32, 256, 0, stream>>>(ffh, w2 + (size_t)l*FF_*C_, x);
    }

    k_finalmask<<<(SQ_*C_)/256, 256, 0, stream>>>(x, qmask, out + (size_t)T_*PTC_);
    k_token<<<T_, 384, 0, stream>>>(x, q2a_idx, q2a_mask, dmask, w_aggr, out);
}

// Round 5
// 748.864 us; speedup vs baseline: 5.1720x; 2.4838x over previous
//
#include <hip/hip_runtime.h>
#include <hip/hip_bf16.h>

#define T_ 768
#define A_ 24
#define S_ 576
#define Q_ 32
#define K_ 128
#define C_ 128
#define H_ 4
#define DH_ 32
#define L_ 3
#define PAIR_ 16
#define PTC_ 384
#define FF_ 256
#define SQ_ (S_*Q_)
#define SK_ (S_*K_)

typedef __attribute__((ext_vector_type(8))) short bf16x8;
typedef __attribute__((ext_vector_type(4))) float f32x4;
typedef unsigned short ushort_t;

#define MFMA(a,b,c) __builtin_amdgcn_mfma_f32_16x16x32_bf16(a,b,c,0,0,0)

__device__ inline unsigned short f2b(float f) {
    union { float f; unsigned u; } v; v.f = f;
    unsigned u = v.u;
    return (unsigned short)((u + 0x7FFFu + ((u >> 16) & 1u)) >> 16);
}

// stage weights w[K][N] (f32 row-major) -> LDS wT[n][k] bf16, XOR-swizzled
template<int KD, int ND>
__device__ inline void stage_wT(const float* __restrict__ w, unsigned short* lds) {
    for (int e = threadIdx.x; e < KD*ND; e += 256) {
        int k = e / ND, n = e % ND;                 // coalesced read over n
        int byte = ((n*KD + k)*2) ^ ((n & 7) << 4);
        *(unsigned short*)((char*)lds + byte) = f2b(w[e]);
    }
}

// stage TR contiguous rows of src (row stride KD f32) -> LDS bf16 [row][k] swizzled
template<int KD, int TR>
__device__ inline void stage_rows(const float* __restrict__ src, size_t r0, unsigned short* lds) {
    for (int e4 = threadIdx.x; e4 < TR*(KD/4); e4 += 256) {
        int row = e4 / (KD/4), c4 = e4 % (KD/4);
        float4 v = ((const float4*)src)[(r0 + row)*(KD/4) + c4];
        int byte = ((row*KD + c4*4)*2) ^ ((row & 7) << 4);
        unsigned short* p = (unsigned short*)((char*)lds + byte);
        p[0]=f2b(v.x); p[1]=f2b(v.y); p[2]=f2b(v.z); p[3]=f2b(v.w);
    }
}

// load one MFMA fragment (8 bf16 along k) from swizzled LDS tile with row-length KD
template<int KD>
__device__ inline bf16x8 ldfrag(const unsigned short* lds, int row, int k) {
    int byte = ((row*KD + k)*2) ^ ((row & 7) << 4);
    return *(const bf16x8*)((const char*)lds + byte);
}

// ---------------- init: x = (gather(token_atoms) @ w_pos) * qm + qsc ----------------
__global__ void k_init_x(const int* __restrict__ a2q_idx, const int* __restrict__ a2q_mask,
                         const int* __restrict__ qmask, const float* __restrict__ ta_act,
                         const float* __restrict__ qsc, const float* __restrict__ w_pos,
                         float* __restrict__ x) {
    int i = blockIdx.x * blockDim.x + threadIdx.x;   // over SQ_*C_
    if (i >= SQ_ * C_) return;
    int r = i / C_, c = i % C_;
    float v = 0.f;
    if (a2q_mask[r]) {
        int idx = a2q_idx[r];
        float p0 = ta_act[idx*3+0], p1 = ta_act[idx*3+1], p2 = ta_act[idx*3+2];
        v = p0 * w_pos[c] + p1 * w_pos[C_+c] + p2 * w_pos[2*C_+c];
    }
    v *= (float)qmask[r];
    x[i] = v + qsc[i];
}

// ---------------- LayerNorm: xn = LN(x) * s + b, one row per block (128 thr) ----------------
__global__ void k_ln(const float* __restrict__ x, const float* __restrict__ s,
                     const float* __restrict__ b, float* __restrict__ xn) {
    int r = blockIdx.x;
    int c = threadIdx.x;
    __shared__ float red[C_];
    float v = x[(size_t)r*C_ + c];
    red[c] = v; __syncthreads();
    for (int off = 64; off > 0; off >>= 1) { if (c < off) red[c] += red[c+off]; __syncthreads(); }
    float mean = red[0] * (1.0f/C_);
    __syncthreads();
    float d = v - mean;
    red[c] = d*d; __syncthreads();
    for (int off = 64; off > 0; off >>= 1) { if (c < off) red[c] += red[c+off]; __syncthreads(); }
    float var = red[0] * (1.0f/C_);
    xn[(size_t)r*C_ + c] = d * rsqrtf(var + 1e-5f) * s[c] + b[c];
}

// ---------------- q projection via MFMA -> bf16 qb16[s][h][qq][d] ----------------
__global__ __launch_bounds__(256) void k_qproj_m(const float* __restrict__ xn,
                                                 const float* __restrict__ wq,
                                                 ushort_t* __restrict__ qb16) {
    __shared__ unsigned short wT[C_*C_];   // 32 KB
    __shared__ unsigned short at[64*C_];   // 16 KB
    stage_wT<C_, C_>(wq, wT);
    size_t r0 = (size_t)blockIdx.x * 64;
    __syncthreads();
    stage_rows<C_, 64>(xn, r0, at);
    __syncthreads();
    int t = threadIdx.x, wid = t>>6, lane = t&63, lr = lane&15, g = lane>>4;
    int mh = (wid&1)*32, nh = (wid>>1)*64;
    f32x4 acc[2][4] = {};
    #pragma unroll
    for (int ks = 0; ks < 4; ks++) {
        int ka = ks*32 + g*8;
        bf16x8 a0 = ldfrag<C_>(at, mh + lr, ka);
        bf16x8 a1 = ldfrag<C_>(at, mh + 16 + lr, ka);
        #pragma unroll
        for (int nt = 0; nt < 4; nt++) {
            bf16x8 b = ldfrag<C_>(wT, nh + nt*16 + lr, ka);
            acc[0][nt] = MFMA(a0, b, acc[0][nt]);
            acc[1][nt] = MFMA(a1, b, acc[1][nt]);
        }
    }
    const float scale = 0.17677669529663687f;  // 1/sqrt(32)
    #pragma unroll
    for (int mt = 0; mt < 2; mt++)
    #pragma unroll
    for (int nt = 0; nt < 4; nt++)
    #pragma unroll
    for (int r = 0; r < 4; r++) {
        int row = (int)r0 + mh + mt*16 + g*4 + r;
        int col = nh + nt*16 + lr;
        int s = row>>5, qq = row&31, h = col>>5, dd = col&31;
        qb16[(((size_t)s*H_ + h)*Q_ + qq)*DH_ + dd] = f2b(acc[mt][nt][r] * scale);
    }
}

// ------- fused keys gather + K/V projection via MFMA -> bf16 kb16[s][h][kk][d], vT16[s][h][d][kk] -------
__global__ __launch_bounds__(256) void k_kv_m(const float* __restrict__ xn,
    const int* __restrict__ q2k_idx, const int* __restrict__ q2k_mask,
    const float* __restrict__ ksc,
    const float* __restrict__ wk, const float* __restrict__ wv,
    ushort_t* __restrict__ kb16, ushort_t* __restrict__ vT16) {
    __shared__ unsigned short wkT[C_*C_];  // 32 KB
    __shared__ unsigned short wvT[C_*C_];  // 32 KB
    __shared__ unsigned short at[64*C_];   // 16 KB
    stage_wT<C_, C_>(wk, wkT);
    stage_wT<C_, C_>(wv, wvT);
    int t = threadIdx.x, wid = t>>6, lane = t&63, lr = lane&15, g = lane>>4;
    int mh = (wid&1)*32, nh = (wid>>1)*64;
    for (int tile = blockIdx.x; tile < SK_/64; tile += gridDim.x) {
        int r0 = tile*64;
        __syncthreads();
        // gather + add ksc, stage bf16 swizzled
        for (int e4 = t; e4 < 64*(C_/4); e4 += 256) {
            int row = e4 >> 5, c4 = e4 & 31;
            int gr = r0 + row;
            float4 v;
            if (q2k_mask[gr]) v = ((const float4*)xn)[(size_t)q2k_idx[gr]*(C_/4) + c4];
            else              v = make_float4(0.f, 0.f, 0.f, 0.f);
            float4 kc = ((const float4*)ksc)[(size_t)gr*(C_/4) + c4];
            v.x += kc.x; v.y += kc.y; v.z += kc.z; v.w += kc.w;
            int byte = ((row*C_ + c4*4)*2) ^ ((row & 7) << 4);
            unsigned short* p = (unsigned short*)((char*)at + byte);
            p[0]=f2b(v.x); p[1]=f2b(v.y); p[2]=f2b(v.z); p[3]=f2b(v.w);
        }
        __syncthreads();
        f32x4 acc[2][4][2] = {};
        #pragma unroll
        for (int ks = 0; ks < 4; ks++) {
            int ka = ks*32 + g*8;
            bf16x8 a0 = ldfrag<C_>(at, mh + lr, ka);
            bf16x8 a1 = ldfrag<C_>(at, mh + 16 + lr, ka);
            #pragma unroll
            for (int nt = 0; nt < 4; nt++) {
                bf16x8 bk = ldfrag<C_>(wkT, nh + nt*16 + lr, ka);
                bf16x8 bv = ldfrag<C_>(wvT, nh + nt*16 + lr, ka);
                acc[0][nt][0] = MFMA(a0, bk, acc[0][nt][0]);
                acc[1][nt][0] = MFMA(a1, bk, acc[1][nt][0]);
                acc[0][nt][1] = MFMA(a0, bv, acc[0][nt][1]);
                acc[1][nt][1] = MFMA(a1, bv, acc[1][nt][1]);
            }
        }
        #pragma unroll
        for (int mt = 0; mt < 2; mt++)
        #pragma unroll
        for (int nt = 0; nt < 4; nt++)
        #pragma unroll
        for (int r = 0; r < 4; r++) {
            int row = r0 + mh + mt*16 + g*4 + r;
            int col = nh + nt*16 + lr;
            int s = row>>7, kk = row&127, h = col>>5, dd = col&31;
            kb16[(((size_t)s*H_ + h)*K_ + kk)*DH_ + dd] = f2b(acc[mt][nt][0][r]);
            vT16[(((size_t)s*H_ + h)*DH_ + dd)*K_ + kk] = f2b(acc[mt][nt][1][r]);
        }
    }
}

// ---------------- MFMA attention: 1 subset/block, 1 head/wave ----------------
__global__ __launch_bounds__(256) void k_attn_m(
    const ushort_t* __restrict__ qb16, const ushort_t* __restrict__ kb16,
    const ushort_t* __restrict__ vT16, const float* __restrict__ pair,
    const int* __restrict__ kmask_g, const float* __restrict__ wpair,
    const float* __restrict__ wo, float* __restrict__ x) {
    __shared__ unsigned short P_lds[H_][Q_*K_];    // 32 KB, swizzled per head
    __shared__ unsigned short O_lds[Q_*C_];        // 8 KB, swizzled
    __shared__ unsigned short woT[C_*C_];          // 32 KB, swizzled [c][hd]
    int s = blockIdx.x, t = threadIdx.x;
    int w = t>>6, lane = t&63, lr = lane&15, g = lane>>4;

    // stage woT cooperatively (read coalesced over c)
    for (int e = t; e < C_*C_; e += 256) {
        int hd = e >> 7, c = e & 127;
        int byte = ((c*C_ + hd)*2) ^ ((c & 7) << 4);
        *(unsigned short*)((char*)woT + byte) = f2b(wo[e]);
    }

    // per-head pair weights (wave-uniform)
    float wp[PAIR_];
    #pragma unroll
    for (int p = 0; p < PAIR_; p++) wp[p] = wpair[p*H_ + w];

    // q fragments direct from global
    const ushort_t* qbase = qb16 + ((size_t)(s*H_ + w)*Q_)*DH_;
    bf16x8 aq0 = *(const bf16x8*)(qbase + (size_t)lr*DH_ + g*8);
    bf16x8 aq1 = *(const bf16x8*)(qbase + (size_t)(16+lr)*DH_ + g*8);

    // logits = q @ k^T  (16 MFMAs)
    const ushort_t* kbase = kb16 + ((size_t)(s*H_ + w)*K_)*DH_;
    f32x4 acc[2][8] = {};
    #pragma unroll
    for (int nt = 0; nt < 8; nt++) {
        bf16x8 b = *(const bf16x8*)(kbase + (size_t)(nt*16+lr)*DH_ + g*8);
        acc[0][nt] = MFMA(aq0, b, acc[0][nt]);
        acc[1][nt] = MFMA(aq1, b, acc[1][nt]);
    }

    // key mask per nt (col = nt*16+lr)
    float km[8];
    #pragma unroll
    for (int nt = 0; nt < 8; nt++) km[nt] = (kmask_g[s*K_ + nt*16 + lr] - 1.0f) * 1e9f;

    // pair bias + mask, in D-fragment layout
    const float* pbase = pair + (size_t)s*Q_*K_*PAIR_;
    #pragma unroll
    for (int mt = 0; mt < 2; mt++)
    #pragma unroll
    for (int r = 0; r < 4; r++) {
        int qq = mt*16 + g*4 + r;
        #pragma unroll
        for (int nt = 0; nt < 8; nt++) {
            int kk = nt*16 + lr;
            const float4* pp = (const float4*)(pbase + ((size_t)qq*K_ + kk)*PAIR_);
            float4 p0 = pp[0], p1 = pp[1], p2 = pp[2], p3 = pp[3];
            float b = p0.x*wp[0] + p0.y*wp[1] + p0.z*wp[2] + p0.w*wp[3]
                    + p1.x*wp[4] + p1.y*wp[5] + p1.z*wp[6] + p1.w*wp[7]
                    + p2.x*wp[8] + p2.y*wp[9] + p2.z*wp[10] + p2.w*wp[11]
                    + p3.x*wp[12] + p3.y*wp[13] + p3.z*wp[14] + p3.w*wp[15];
            acc[mt][nt][r] += b + km[nt];
        }
    }

    // in-register softmax over kk (16 lanes x 8 nt per row)
    float inv[2][4];
    #pragma unroll
    for (int mt = 0; mt < 2; mt++)
    #pragma unroll
    for (int r = 0; r < 4; r++) {
        float mx = acc[mt][0][r];
        #pragma unroll
        for (int nt = 1; nt < 8; nt++) mx = fmaxf(mx, acc[mt][nt][r]);
        #pragma unroll
        for (int m = 1; m <= 8; m <<= 1) mx = fmaxf(mx, __shfl_xor(mx, m));
        float sum = 0.f;
        #pragma unroll
        for (int nt = 0; nt < 8; nt++) {
            float e = __expf(acc[mt][nt][r] - mx);
            acc[mt][nt][r] = e;
            sum += e;
        }
        #pragma unroll
        for (int m = 1; m <= 8; m <<= 1) sum += __shfl_xor(sum, m);
        inv[mt][r] = 1.0f / sum;
    }

    // P -> own LDS region (bf16, swizzled); same-wave write->read, no barrier needed
    unsigned short* Pb = &P_lds[w][0];
    #pragma unroll
    for (int mt = 0; mt < 2; mt++)
    #pragma unroll
    for (int r = 0; r < 4; r++) {
        int row = mt*16 + g*4 + r;
        #pragma unroll
        for (int nt = 0; nt < 8; nt++) {
            int byte = ((row*K_ + nt*16 + lr)*2) ^ ((row & 7) << 4);
            *(unsigned short*)((char*)Pb + byte) = f2b(acc[mt][nt][r]);
        }
    }

    // PV: P(32x128) @ v^T-frags (d = col), v direct from global
    const ushort_t* vbase = vT16 + ((size_t)(s*H_ + w)*DH_)*K_;
    f32x4 po[2][2] = {};
    #pragma unroll
    for (int ks = 0; ks < 4; ks++) {
        int kk0 = ks*32 + g*8;
        bf16x8 a0 = ldfrag<K_>(Pb, lr, kk0);
        bf16x8 a1 = ldfrag<K_>(Pb, 16 + lr, kk0);
        #pragma unroll
        for (int nt = 0; nt < 2; nt++) {
            bf16x8 b = *(const bf16x8*)(vbase + (size_t)(nt*16+lr)*K_ + kk0);
            po[0][nt] = MFMA(a0, b, po[0][nt]);
            po[1][nt] = MFMA(a1, b, po[1][nt]);
        }
    }

    // O -> LDS (normalize by 1/sum here)
    #pragma unroll
    for (int mt = 0; mt < 2; mt++)
    #pragma unroll
    for (int nt = 0; nt < 2; nt++)
    #pragma unroll
    for (int r = 0; r < 4; r++) {
        int row = mt*16 + g*4 + r;
        int col = w*32 + nt*16 + lr;
        int byte = ((row*C_ + col)*2) ^ ((row & 7) << 4);
        *(unsigned short*)((char*)O_lds + byte) = f2b(po[mt][nt][r] * inv[mt][r]);
    }
    __syncthreads();

    // output projection: wave w -> cols w*32..w*32+31
    f32x4 fo[2][2] = {};
    #pragma unroll
    for (int ks = 0; ks < 4; ks++) {
        int k0 = ks*32 + g*8;
        bf16x8 a0 = ldfrag<C_>(O_lds, lr, k0);
        bf16x8 a1 = ldfrag<C_>(O_lds, 16 + lr, k0);
        #pragma unroll
        for (int nt = 0; nt < 2; nt++) {
            bf16x8 b = ldfrag<C_>(woT, w*32 + nt*16 + lr, k0);
            fo[0][nt] = MFMA(a0, b, fo[0][nt]);
            fo[1][nt] = MFMA(a1, b, fo[1][nt]);
        }
    }
    #pragma unroll
    for (int mt = 0; mt < 2; mt++)
    #pragma unroll
    for (int nt = 0; nt < 2; nt++)
    #pragma unroll
    for (int r = 0; r < 4; r++) {
        int row = mt*16 + g*4 + r;
        int col = w*32 + nt*16 + lr;
        x[((size_t)s*Q_ + row)*C_ + col] += fo[mt][nt][r];
    }
}

// ---------------- FF1 via MFMA: ffh = relu(xn2 @ w1) ----------------
__global__ __launch_bounds__(256) void k_ff1_m(const float* __restrict__ xn,
                                               const float* __restrict__ w1,
                                               float* __restrict__ ffh) {
    __shared__ unsigned short wT[C_*FF_];  // [n=256][k=128] 64 KB
    __shared__ unsigned short at[64*C_];   // 16 KB
    stage_wT<C_, FF_>(w1, wT);
    size_t r0 = (size_t)blockIdx.x * 64;
    __syncthreads();
    stage_rows<C_, 64>(xn, r0, at);
    __syncthreads();
    int t = threadIdx.x, wid = t>>6, lane = t&63, lr = lane&15, g = lane>>4;
    int mh = (wid&1)*32, nh = (wid>>1)*128;
    f32x4 acc[2][8] = {};
    #pragma unroll
    for (int ks = 0; ks < 4; ks++) {
        int ka = ks*32 + g*8;
        bf16x8 a0 = ldfrag<C_>(at, mh + lr, ka);
        bf16x8 a1 = ldfrag<C_>(at, mh + 16 + lr, ka);
        #pragma unroll
        for (int nt = 0; nt < 8; nt++) {
            bf16x8 b = ldfrag<C_>(wT, nh + nt*16 + lr, ka);
            acc[0][nt] = MFMA(a0, b, acc[0][nt]);
            acc[1][nt] = MFMA(a1, b, acc[1][nt]);
        }
    }
    #pragma unroll
    for (int mt = 0; mt < 2; mt++)
    #pragma unroll
    for (int nt = 0; nt < 8; nt++)
    #pragma unroll
    for (int r = 0; r < 4; r++) {
        int row = (int)r0 + mh + mt*16 + g*4 + r;
        int col = nh + nt*16 + lr;
        ffh[(size_t)row*FF_ + col] = fmaxf(acc[mt][nt][r], 0.f);
    }
}

// ---------------- FF2 via MFMA: x += ffh @ w2 ----------------
__global__ __launch_bounds__(256) void k_ff2_m(const float* __restrict__ ffh,
                                               const float* __restrict__ w2,
                                               float* __restrict__ x) {
    __shared__ unsigned short wT[FF_*C_];  // [n=128][k=256] 64 KB
    __shared__ unsigned short at[32*FF_];  // 16 KB
    stage_wT<FF_, C_>(w2, wT);
    size_t r0 = (size_t)blockIdx.x * 32;
    __syncthreads();
    stage_rows<FF_, 32>(ffh, r0, at);
    __syncthreads();
    int t = threadIdx.x, wid = t>>6, lane = t&63, lr = lane&15, g = lane>>4;
    int nq = wid*32;
    f32x4 acc[2][2] = {};
    #pragma unroll
    for (int ks = 0; ks < 8; ks++) {
        int ka = ks*32 + g*8;
        bf16x8 a0 = ldfrag<FF_>(at, lr, ka);
        bf16x8 a1 = ldfrag<FF_>(at, 16 + lr, ka);
        #pragma unroll
        for (int nt = 0; nt < 2; nt++) {
            bf16x8 b = ldfrag<FF_>(wT, nq + nt*16 + lr, ka);
            acc[0][nt] = MFMA(a0, b, acc[0][nt]);
            acc[1][nt] = MFMA(a1, b, acc[1][nt]);
        }
    }
    #pragma unroll
    for (int mt = 0; mt < 2; mt++)
    #pragma unroll
    for (int nt = 0; nt < 2; nt++)
    #pragma unroll
    for (int r = 0; r < 4; r++) {
        int row = (int)r0 + mt*16 + g*4 + r;
        int col = nq + nt*16 + lr;
        x[(size_t)row*C_ + col] += acc[mt][nt][r];
    }
}

// ---------------- final mask + write skip (f32 out) ----------------
__global__ void k_finalmask(float* __restrict__ x, const int* __restrict__ qmask,
                            float* __restrict__ out_skip) {
    int i = blockIdx.x * blockDim.x + threadIdx.x;
    if (i >= SQ_*C_) return;
    float v = x[i] * (float)qmask[i / C_];
    x[i] = v;
    out_skip[i] = v;
}

// ---------------- token aggregation (f32 out) ----------------
__global__ __launch_bounds__(384) void k_token(const float* __restrict__ x, const int* __restrict__ q2a_idx,
                                               const int* __restrict__ q2a_mask, const int* __restrict__ dmask,
                                               const float* __restrict__ w_aggr, float* __restrict__ out) {
    __shared__ float xs[A_][C_];
    __shared__ float am[A_];
    int tt = blockIdx.x;
    int t = threadIdx.x;
    for (int e = t; e < A_*C_; e += 384) {
        int a = e >> 7, c = e & 127;
        int idx = q2a_idx[tt*A_ + a];
        int gm  = q2a_mask[tt*A_ + a];
        xs[a][c] = gm ? x[(size_t)idx*C_ + c] : 0.f;
    }
    if (t < A_) am[t] = (float)dmask[tt*A_ + t];
    __syncthreads();
    float acc[A_];
    #pragma unroll
    for (int a = 0; a < A_; a++) acc[a] = 0.f;
    for (int c = 0; c < C_; c++) {
        float wv = w_aggr[c*PTC_ + t];
        #pragma unroll
        for (int a = 0; a < A_; a++) acc[a] += xs[a][c] * wv;
    }
    float denom = 1e-10f, num = 0.f;
    #pragma unroll
    for (int a = 0; a < A_; a++) { denom += am[a]; num += am[a] * fmaxf(acc[a], 0.f); }
    out[(size_t)tt*PTC_ + t] = num / denom;
}

extern "C" void kernel_launch(void* const* d_in, const int* in_sizes, int n_in,
                              void* d_out, int out_size, void* d_ws, size_t ws_size,
                              hipStream_t stream) {
    const int*   qmask    = (const int*)d_in[0];
    const int*   dmask    = (const int*)d_in[1];
    const int*   a2q_idx  = (const int*)d_in[2];
    const int*   a2q_mask = (const int*)d_in[3];
    const int*   q2k_idx  = (const int*)d_in[4];
    const int*   q2k_mask = (const int*)d_in[5];
    const int*   q2a_idx  = (const int*)d_in[6];
    const int*   q2a_mask = (const int*)d_in[7];
    const float* ta_act   = (const float*)d_in[8];
    const float* qsc      = (const float*)d_in[9];
    const float* pair     = (const float*)d_in[10];
    const int*   kmask    = (const int*)d_in[11];
    const float* ksc      = (const float*)d_in[12];
    const float* w_pos    = (const float*)d_in[13];
    const float* w_aggr   = (const float*)d_in[14];
    const float* ln1_s    = (const float*)d_in[15];
    const float* ln1_b    = (const float*)d_in[16];
    const float* wq       = (const float*)d_in[17];
    const float* wk       = (const float*)d_in[18];
    const float* wv       = (const float*)d_in[19];
    const float* wpair    = (const float*)d_in[20];
    const float* wo       = (const float*)d_in[21];
    const float* ln2_s    = (const float*)d_in[22];
    const float* ln2_b    = (const float*)d_in[23];
    const float* w1       = (const float*)d_in[24];
    const float* w2       = (const float*)d_in[25];
    float* out = (float*)d_out;

    float* ws = (float*)d_ws;
    float*    x     = ws;                                     // SQ*C f32
    float*    xn    = x + (size_t)SQ_*C_;                     // SQ*C f32
    ushort_t* qb16  = (ushort_t*)(xn + (size_t)SQ_*C_);       // SQ*C bf16
    ushort_t* kb16  = qb16 + (size_t)SQ_*C_;                  // S*H*K*DH bf16
    ushort_t* vT16  = kb16 + (size_t)S_*H_*K_*DH_;            // S*H*DH*K bf16
    float*    ffh   = (float*)kb16;                           // alias (dead after attn)

    k_init_x<<<(SQ_*C_)/256, 256, 0, stream>>>(a2q_idx, a2q_mask, qmask, ta_act, qsc, w_pos, x);

    for (int l = 0; l < L_; l++) {
        k_ln<<<SQ_, 128, 0, stream>>>(x, ln1_s + l*C_, ln1_b + l*C_, xn);
        k_qproj_m<<<SQ_/64, 256, 0, stream>>>(xn, wq + (size_t)l*C_*C_, qb16);
        k_kv_m<<<576, 256, 0, stream>>>(xn, q2k_idx, q2k_mask, ksc,
                                        wk + (size_t)l*C_*C_, wv + (size_t)l*C_*C_, kb16, vT16);
        k_attn_m<<<S_, 256, 0, stream>>>(qb16, kb16, vT16, pair, kmask,
                                         wpair + l*PAIR_*H_, wo + (size_t)l*C_*C_, x);
        k_ln<<<SQ_, 128, 0, stream>>>(x, ln2_s + l*C_, ln2_b + l*C_, xn);
        k_ff1_m<<<SQ_/64, 256, 0, stream>>>(xn, w1 + (size_t)l*C_*FF_, ffh);
        k_ff2_m<<<SQ_/32, 256, 0, stream>>>(ffh, w2 + (size_t)l*FF_*C_, x);
    }

    k_finalmask<<<(SQ_*C_)/256, 256, 0, stream>>>(x, qmask, out + (size_t)T_*PTC_);
    k_token<<<T_, 384, 0, stream>>>(x, q2a_idx, q2a_mask, dmask, w_aggr, out);
}

// Round 6
// 670.726 us; speedup vs baseline: 5.7745x; 1.1165x over previous
//
#include <hip/hip_runtime.h>
#include <hip/hip_bf16.h>

#define T_ 768
#define A_ 24
#define S_ 576
#define Q_ 32
#define K_ 128
#define C_ 128
#define H_ 4
#define DH_ 32
#define L_ 3
#define PAIR_ 16
#define PTC_ 384
#define FF_ 256
#define SQ_ (S_*Q_)
#define SK_ (S_*K_)

typedef __attribute__((ext_vector_type(8))) short bf16x8;
typedef __attribute__((ext_vector_type(4))) float f32x4;
typedef unsigned short ushort_t;

#define MFMA(a,b,c) __builtin_amdgcn_mfma_f32_16x16x32_bf16(a,b,c,0,0,0)

__device__ inline unsigned short f2b(float f) {
    union { float f; unsigned u; } v; v.f = f;
    unsigned u = v.u;
    return (unsigned short)((u + 0x7FFFu + ((u >> 16) & 1u)) >> 16);
}
__device__ inline float b2f(unsigned short b) {
    union { unsigned u; float f; } v; v.u = ((unsigned)b) << 16;
    return v.f;
}

// stage weights w[K][N] (f32 row-major) -> LDS wT[n][k] bf16, XOR-swizzled
template<int KD, int ND>
__device__ inline void stage_wT(const float* __restrict__ w, unsigned short* lds) {
    for (int e = threadIdx.x; e < KD*ND; e += 256) {
        int k = e / ND, n = e % ND;                 // coalesced read over n
        int byte = ((n*KD + k)*2) ^ ((n & 7) << 4);
        *(unsigned short*)((char*)lds + byte) = f2b(w[e]);
    }
}

// stage TR contiguous rows of src (row stride KD f32) -> LDS bf16 [row][k] swizzled
template<int KD, int TR>
__device__ inline void stage_rows(const float* __restrict__ src, size_t r0, unsigned short* lds) {
    for (int e4 = threadIdx.x; e4 < TR*(KD/4); e4 += 256) {
        int row = e4 / (KD/4), c4 = e4 % (KD/4);
        float4 v = ((const float4*)src)[(r0 + row)*(KD/4) + c4];
        int byte = ((row*KD + c4*4)*2) ^ ((row & 7) << 4);
        unsigned short* p = (unsigned short*)((char*)lds + byte);
        p[0]=f2b(v.x); p[1]=f2b(v.y); p[2]=f2b(v.z); p[3]=f2b(v.w);
    }
}

// load one MFMA fragment (8 bf16 along k) from swizzled LDS tile with row-length KD
template<int KD>
__device__ inline bf16x8 ldfrag(const unsigned short* lds, int row, int k) {
    int byte = ((row*KD + k)*2) ^ ((row & 7) << 4);
    return *(const bf16x8*)((const char*)lds + byte);
}

// ---------------- init: x = (gather(token_atoms) @ w_pos) * qm + qsc ----------------
__global__ void k_init_x(const int* __restrict__ a2q_idx, const int* __restrict__ a2q_mask,
                         const int* __restrict__ qmask, const float* __restrict__ ta_act,
                         const float* __restrict__ qsc, const float* __restrict__ w_pos,
                         float* __restrict__ x) {
    int i = blockIdx.x * blockDim.x + threadIdx.x;   // over SQ_*C_
    if (i >= SQ_ * C_) return;
    int r = i / C_, c = i % C_;
    float v = 0.f;
    if (a2q_mask[r]) {
        int idx = a2q_idx[r];
        float p0 = ta_act[idx*3+0], p1 = ta_act[idx*3+1], p2 = ta_act[idx*3+2];
        v = p0 * w_pos[c] + p1 * w_pos[C_+c] + p2 * w_pos[2*C_+c];
    }
    v *= (float)qmask[r];
    x[i] = v + qsc[i];
}

// ---------------- LayerNorm ----------------
__global__ void k_ln(const float* __restrict__ x, const float* __restrict__ s,
                     const float* __restrict__ b, float* __restrict__ xn) {
    int r = blockIdx.x;
    int c = threadIdx.x;
    __shared__ float red[C_];
    float v = x[(size_t)r*C_ + c];
    red[c] = v; __syncthreads();
    for (int off = 64; off > 0; off >>= 1) { if (c < off) red[c] += red[c+off]; __syncthreads(); }
    float mean = red[0] * (1.0f/C_);
    __syncthreads();
    float d = v - mean;
    red[c] = d*d; __syncthreads();
    for (int off = 64; off > 0; off >>= 1) { if (c < off) red[c] += red[c+off]; __syncthreads(); }
    float var = red[0] * (1.0f/C_);
    xn[(size_t)r*C_ + c] = d * rsqrtf(var + 1e-5f) * s[c] + b[c];
}

// ---------------- pair-bias precompute: bias16[l][s][h][qq][kk] = pair . wpair ----------------
__global__ __launch_bounds__(256) void k_bias(const float* __restrict__ pair,
                                              const float* __restrict__ wpair,
                                              ushort_t* __restrict__ bias16) {
    int s  = blockIdx.x >> 4;
    int qq = (blockIdx.x & 15)*2 + (threadIdx.x >> 7);
    int kk = threadIdx.x & 127;
    const float4* pp = (const float4*)(pair + (((size_t)s*Q_ + qq)*K_ + kk)*PAIR_);
    float4 p0 = pp[0], p1 = pp[1], p2 = pp[2], p3 = pp[3];
    float pv[PAIR_] = {p0.x,p0.y,p0.z,p0.w, p1.x,p1.y,p1.z,p1.w,
                       p2.x,p2.y,p2.z,p2.w, p3.x,p3.y,p3.z,p3.w};
    #pragma unroll
    for (int l = 0; l < L_; l++)
    #pragma unroll
    for (int h = 0; h < H_; h++) {
        float acc = 0.f;
        #pragma unroll
        for (int p = 0; p < PAIR_; p++) acc += pv[p] * wpair[l*PAIR_*H_ + p*H_ + h];
        bias16[(((size_t)l*S_ + s)*H_ + h)*(Q_*K_) + qq*K_ + kk] = f2b(acc);
    }
}

// ---------------- woT16[l][c][hd] = bf16(wo[l][hd][c]) ----------------
__global__ void k_woT(const float* __restrict__ wo, ushort_t* __restrict__ woT16) {
    int e = blockIdx.x * 256 + threadIdx.x;   // over L_*C_*C_
    int l = e / (C_*C_), rem = e % (C_*C_);
    int c = rem >> 7, hd = rem & 127;
    woT16[e] = f2b(wo[(size_t)l*C_*C_ + hd*C_ + c]);
}

// ---------------- q projection via MFMA -> bf16 qb16[s][h][qq][d] ----------------
__global__ __launch_bounds__(256) void k_qproj_m(const float* __restrict__ xn,
                                                 const float* __restrict__ wq,
                                                 ushort_t* __restrict__ qb16) {
    __shared__ unsigned short wT[C_*C_];   // 32 KB
    __shared__ unsigned short at[64*C_];   // 16 KB
    stage_wT<C_, C_>(wq, wT);
    size_t r0 = (size_t)blockIdx.x * 64;
    __syncthreads();
    stage_rows<C_, 64>(xn, r0, at);
    __syncthreads();
    int t = threadIdx.x, wid = t>>6, lane = t&63, lr = lane&15, g = lane>>4;
    int mh = (wid&1)*32, nh = (wid>>1)*64;
    f32x4 acc[2][4] = {};
    #pragma unroll
    for (int ks = 0; ks < 4; ks++) {
        int ka = ks*32 + g*8;
        bf16x8 a0 = ldfrag<C_>(at, mh + lr, ka);
        bf16x8 a1 = ldfrag<C_>(at, mh + 16 + lr, ka);
        #pragma unroll
        for (int nt = 0; nt < 4; nt++) {
            bf16x8 b = ldfrag<C_>(wT, nh + nt*16 + lr, ka);
            acc[0][nt] = MFMA(a0, b, acc[0][nt]);
            acc[1][nt] = MFMA(a1, b, acc[1][nt]);
        }
    }
    const float scale = 0.17677669529663687f;  // 1/sqrt(32)
    #pragma unroll
    for (int mt = 0; mt < 2; mt++)
    #pragma unroll
    for (int nt = 0; nt < 4; nt++)
    #pragma unroll
    for (int r = 0; r < 4; r++) {
        int row = (int)r0 + mh + mt*16 + g*4 + r;
        int col = nh + nt*16 + lr;
        int s = row>>5, qq = row&31, h = col>>5, dd = col&31;
        qb16[(((size_t)s*H_ + h)*Q_ + qq)*DH_ + dd] = f2b(acc[mt][nt][r] * scale);
    }
}

// ------- fused keys gather + K/V projection via MFMA -> kb16[s][h][kk][d], vT16[s][h][d][kk] -------
__global__ __launch_bounds__(256) void k_kv_m(const float* __restrict__ xn,
    const int* __restrict__ q2k_idx, const int* __restrict__ q2k_mask,
    const float* __restrict__ ksc,
    const float* __restrict__ wk, const float* __restrict__ wv,
    ushort_t* __restrict__ kb16, ushort_t* __restrict__ vT16) {
    __shared__ unsigned short wkT[C_*C_];  // 32 KB
    __shared__ unsigned short wvT[C_*C_];  // 32 KB
    __shared__ unsigned short at[64*C_];   // 16 KB
    stage_wT<C_, C_>(wk, wkT);
    stage_wT<C_, C_>(wv, wvT);
    int t = threadIdx.x, wid = t>>6, lane = t&63, lr = lane&15, g = lane>>4;
    int mh = (wid&1)*32, nh = (wid>>1)*64;
    for (int tile = blockIdx.x; tile < SK_/64; tile += gridDim.x) {
        int r0 = tile*64;
        __syncthreads();
        for (int e4 = t; e4 < 64*(C_/4); e4 += 256) {
            int row = e4 >> 5, c4 = e4 & 31;
            int gr = r0 + row;
            float4 v;
            if (q2k_mask[gr]) v = ((const float4*)xn)[(size_t)q2k_idx[gr]*(C_/4) + c4];
            else              v = make_float4(0.f, 0.f, 0.f, 0.f);
            float4 kc = ((const float4*)ksc)[(size_t)gr*(C_/4) + c4];
            v.x += kc.x; v.y += kc.y; v.z += kc.z; v.w += kc.w;
            int byte = ((row*C_ + c4*4)*2) ^ ((row & 7) << 4);
            unsigned short* p = (unsigned short*)((char*)at + byte);
            p[0]=f2b(v.x); p[1]=f2b(v.y); p[2]=f2b(v.z); p[3]=f2b(v.w);
        }
        __syncthreads();
        f32x4 acc[2][4][2] = {};
        #pragma unroll
        for (int ks = 0; ks < 4; ks++) {
            int ka = ks*32 + g*8;
            bf16x8 a0 = ldfrag<C_>(at, mh + lr, ka);
            bf16x8 a1 = ldfrag<C_>(at, mh + 16 + lr, ka);
            #pragma unroll
            for (int nt = 0; nt < 4; nt++) {
                bf16x8 bk = ldfrag<C_>(wkT, nh + nt*16 + lr, ka);
                bf16x8 bv = ldfrag<C_>(wvT, nh + nt*16 + lr, ka);
                acc[0][nt][0] = MFMA(a0, bk, acc[0][nt][0]);
                acc[1][nt][0] = MFMA(a1, bk, acc[1][nt][0]);
                acc[0][nt][1] = MFMA(a0, bv, acc[0][nt][1]);
                acc[1][nt][1] = MFMA(a1, bv, acc[1][nt][1]);
            }
        }
        #pragma unroll
        for (int mt = 0; mt < 2; mt++)
        #pragma unroll
        for (int nt = 0; nt < 4; nt++)
        #pragma unroll
        for (int r = 0; r < 4; r++) {
            int row = r0 + mh + mt*16 + g*4 + r;
            int col = nh + nt*16 + lr;
            int s = row>>7, kk = row&127, h = col>>5, dd = col&31;
            kb16[(((size_t)s*H_ + h)*K_ + kk)*DH_ + dd] = f2b(acc[mt][nt][0][r]);
            vT16[(((size_t)s*H_ + h)*DH_ + dd)*K_ + kk] = f2b(acc[mt][nt][1][r]);
        }
    }
}

// ---------------- MFMA attention: 1 subset/block, 1 head/wave; precomputed bias ----------------
__global__ __launch_bounds__(256) void k_attn_m(
    const ushort_t* __restrict__ qb16, const ushort_t* __restrict__ kb16,
    const ushort_t* __restrict__ vT16, const ushort_t* __restrict__ bias16,
    const int* __restrict__ kmask_g, const ushort_t* __restrict__ woT16,
    float* __restrict__ x) {
    __shared__ unsigned short BP[H_][Q_*K_];   // 32 KB: bias, then P (per-head plane)
    __shared__ unsigned short O_lds[Q_*C_];    // 8 KB, swizzled
    int s = blockIdx.x, t = threadIdx.x;
    int w = t>>6, lane = t&63, lr = lane&15, g = lane>>4;

    // stage bias -> LDS, swizzle byte ^= ((qq>>2)&3)<<5  (coalesced global reads)
    {
        const ushort_t* bb = bias16 + (size_t)s*H_*Q_*K_;
        for (int e8 = t; e8 < H_*Q_*K_/8; e8 += 256) {
            int h = e8 >> 9, rem = e8 & 511;
            int qq = rem >> 4, kk0 = (rem & 15)*8;
            bf16x8 v = *(const bf16x8*)(bb + h*(Q_*K_) + qq*K_ + kk0);
            int byte = ((qq*K_ + kk0)*2) ^ (((qq>>2)&3)<<5);
            *(bf16x8*)((char*)&BP[h][0] + byte) = v;
        }
    }

    // q fragments direct from global
    const ushort_t* qbase = qb16 + ((size_t)(s*H_ + w)*Q_)*DH_;
    bf16x8 aq0 = *(const bf16x8*)(qbase + (size_t)lr*DH_ + g*8);
    bf16x8 aq1 = *(const bf16x8*)(qbase + (size_t)(16+lr)*DH_ + g*8);

    // logits = q @ k^T  (16 MFMAs), k direct from global
    const ushort_t* kbase = kb16 + ((size_t)(s*H_ + w)*K_)*DH_;
    f32x4 acc[2][8] = {};
    #pragma unroll
    for (int nt = 0; nt < 8; nt++) {
        bf16x8 b = *(const bf16x8*)(kbase + (size_t)(nt*16+lr)*DH_ + g*8);
        acc[0][nt] = MFMA(aq0, b, acc[0][nt]);
        acc[1][nt] = MFMA(aq1, b, acc[1][nt]);
    }

    // key mask per nt (col = nt*16+lr)
    float km[8];
    #pragma unroll
    for (int nt = 0; nt < 8; nt++) km[nt] = (kmask_g[s*K_ + nt*16 + lr] - 1.0f) * 1e9f;

    __syncthreads();   // bias staged

    // bias add from own plane (D-fragment pattern)
    unsigned short* Pb = &BP[w][0];
    #pragma unroll
    for (int mt = 0; mt < 2; mt++)
    #pragma unroll
    for (int r = 0; r < 4; r++) {
        int qq = mt*16 + g*4 + r;
        #pragma unroll
        for (int nt = 0; nt < 8; nt++) {
            int byte = ((qq*K_ + nt*16 + lr)*2) ^ (((qq>>2)&3)<<5);
            acc[mt][nt][r] += b2f(*(unsigned short*)((char*)Pb + byte)) + km[nt];
        }
    }

    // in-register softmax over kk (16 lanes x 8 nt per row)
    float inv[2][4];
    #pragma unroll
    for (int mt = 0; mt < 2; mt++)
    #pragma unroll
    for (int r = 0; r < 4; r++) {
        float mx = acc[mt][0][r];
        #pragma unroll
        for (int nt = 1; nt < 8; nt++) mx = fmaxf(mx, acc[mt][nt][r]);
        #pragma unroll
        for (int m = 1; m <= 8; m <<= 1) mx = fmaxf(mx, __shfl_xor(mx, m));
        float sum = 0.f;
        #pragma unroll
        for (int nt = 0; nt < 8; nt++) {
            float e = __expf(acc[mt][nt][r] - mx);
            acc[mt][nt][r] = e;
            sum += e;
        }
        #pragma unroll
        for (int m = 1; m <= 8; m <<= 1) sum += __shfl_xor(sum, m);
        inv[mt][r] = 1.0f / sum;
    }

    // P -> own plane (bias fully consumed; same wave, no barrier needed)
    #pragma unroll
    for (int mt = 0; mt < 2; mt++)
    #pragma unroll
    for (int r = 0; r < 4; r++) {
        int row = mt*16 + g*4 + r;
        #pragma unroll
        for (int nt = 0; nt < 8; nt++) {
            int byte = ((row*K_ + nt*16 + lr)*2) ^ ((row & 7) << 4);
            *(unsigned short*)((char*)Pb + byte) = f2b(acc[mt][nt][r]);
        }
    }

    // PV: P(32x128) @ v^T-frags, v direct from global
    const ushort_t* vbase = vT16 + ((size_t)(s*H_ + w)*DH_)*K_;
    f32x4 po[2][2] = {};
    #pragma unroll
    for (int ks = 0; ks < 4; ks++) {
        int kk0 = ks*32 + g*8;
        bf16x8 a0 = ldfrag<K_>(Pb, lr, kk0);
        bf16x8 a1 = ldfrag<K_>(Pb, 16 + lr, kk0);
        #pragma unroll
        for (int nt = 0; nt < 2; nt++) {
            bf16x8 b = *(const bf16x8*)(vbase + (size_t)(nt*16+lr)*K_ + kk0);
            po[0][nt] = MFMA(a0, b, po[0][nt]);
            po[1][nt] = MFMA(a1, b, po[1][nt]);
        }
    }

    // O -> LDS (normalize by 1/sum here)
    #pragma unroll
    for (int mt = 0; mt < 2; mt++)
    #pragma unroll
    for (int nt = 0; nt < 2; nt++)
    #pragma unroll
    for (int r = 0; r < 4; r++) {
        int row = mt*16 + g*4 + r;
        int col = w*32 + nt*16 + lr;
        int byte = ((row*C_ + col)*2) ^ ((row & 7) << 4);
        *(unsigned short*)((char*)O_lds + byte) = f2b(po[mt][nt][r] * inv[mt][r]);
    }
    __syncthreads();

    // output projection: wave w -> cols w*32..w*32+31; wo frags direct from global woT16
    f32x4 fo[2][2] = {};
    #pragma unroll
    for (int ks = 0; ks < 4; ks++) {
        int k0 = ks*32 + g*8;
        bf16x8 a0 = ldfrag<C_>(O_lds, lr, k0);
        bf16x8 a1 = ldfrag<C_>(O_lds, 16 + lr, k0);
        #pragma unroll
        for (int nt = 0; nt < 2; nt++) {
            bf16x8 b = *(const bf16x8*)(woT16 + (size_t)(w*32 + nt*16 + lr)*C_ + k0);
            fo[0][nt] = MFMA(a0, b, fo[0][nt]);
            fo[1][nt] = MFMA(a1, b, fo[1][nt]);
        }
    }
    #pragma unroll
    for (int mt = 0; mt < 2; mt++)
    #pragma unroll
    for (int nt = 0; nt < 2; nt++)
    #pragma unroll
    for (int r = 0; r < 4; r++) {
        int row = mt*16 + g*4 + r;
        int col = w*32 + nt*16 + lr;
        x[((size_t)s*Q_ + row)*C_ + col] += fo[mt][nt][r];
    }
}

// ---------------- FF1 via MFMA: ffh = relu(xn2 @ w1) ----------------
__global__ __launch_bounds__(256) void k_ff1_m(const float* __restrict__ xn,
                                               const float* __restrict__ w1,
                                               float* __restrict__ ffh) {
    __shared__ unsigned short wT[C_*FF_];  // [n=256][k=128] 64 KB
    __shared__ unsigned short at[64*C_];   // 16 KB
    stage_wT<C_, FF_>(w1, wT);
    size_t r0 = (size_t)blockIdx.x * 64;
    __syncthreads();
    stage_rows<C_, 64>(xn, r0, at);
    __syncthreads();
    int t = threadIdx.x, wid = t>>6, lane = t&63, lr = lane&15, g = lane>>4;
    int mh = (wid&1)*32, nh = (wid>>1)*128;
    f32x4 acc[2][8] = {};
    #pragma unroll
    for (int ks = 0; ks < 4; ks++) {
        int ka = ks*32 + g*8;
        bf16x8 a0 = ldfrag<C_>(at, mh + lr, ka);
        bf16x8 a1 = ldfrag<C_>(at, mh + 16 + lr, ka);
        #pragma unroll
        for (int nt = 0; nt < 8; nt++) {
            bf16x8 b = ldfrag<C_>(wT, nh + nt*16 + lr, ka);
            acc[0][nt] = MFMA(a0, b, acc[0][nt]);
            acc[1][nt] = MFMA(a1, b, acc[1][nt]);
        }
    }
    #pragma unroll
    for (int mt = 0; mt < 2; mt++)
    #pragma unroll
    for (int nt = 0; nt < 8; nt++)
    #pragma unroll
    for (int r = 0; r < 4; r++) {
        int row = (int)r0 + mh + mt*16 + g*4 + r;
        int col = nh + nt*16 + lr;
        ffh[(size_t)row*FF_ + col] = fmaxf(acc[mt][nt][r], 0.f);
    }
}

// ---------------- FF2 via MFMA: x += ffh @ w2 ----------------
__global__ __launch_bounds__(256) void k_ff2_m(const float* __restrict__ ffh,
                                               const float* __restrict__ w2,
                                               float* __restrict__ x) {
    __shared__ unsigned short wT[FF_*C_];  // [n=128][k=256] 64 KB
    __shared__ unsigned short at[32*FF_];  // 16 KB
    stage_wT<FF_, C_>(w2, wT);
    size_t r0 = (size_t)blockIdx.x * 32;
    __syncthreads();
    stage_rows<FF_, 32>(ffh, r0, at);
    __syncthreads();
    int t = threadIdx.x, wid = t>>6, lane = t&63, lr = lane&15, g = lane>>4;
    int nq = wid*32;
    f32x4 acc[2][2] = {};
    #pragma unroll
    for (int ks = 0; ks < 8; ks++) {
        int ka = ks*32 + g*8;
        bf16x8 a0 = ldfrag<FF_>(at, lr, ka);
        bf16x8 a1 = ldfrag<FF_>(at, 16 + lr, ka);
        #pragma unroll
        for (int nt = 0; nt < 2; nt++) {
            bf16x8 b = ldfrag<FF_>(wT, nq + nt*16 + lr, ka);
            acc[0][nt] = MFMA(a0, b, acc[0][nt]);
            acc[1][nt] = MFMA(a1, b, acc[1][nt]);
        }
    }
    #pragma unroll
    for (int mt = 0; mt < 2; mt++)
    #pragma unroll
    for (int nt = 0; nt < 2; nt++)
    #pragma unroll
    for (int r = 0; r < 4; r++) {
        int row = (int)r0 + mt*16 + g*4 + r;
        int col = nq + nt*16 + lr;
        x[(size_t)row*C_ + col] += acc[mt][nt][r];
    }
}

// ---------------- final mask + write skip (f32 out) ----------------
__global__ void k_finalmask(float* __restrict__ x, const int* __restrict__ qmask,
                            float* __restrict__ out_skip) {
    int i = blockIdx.x * blockDim.x + threadIdx.x;
    if (i >= SQ_*C_) return;
    float v = x[i] * (float)qmask[i / C_];
    x[i] = v;
    out_skip[i] = v;
}

// ---------------- token aggregation (f32 out) ----------------
__global__ __launch_bounds__(384) void k_token(const float* __restrict__ x, const int* __restrict__ q2a_idx,
                                               const int* __restrict__ q2a_mask, const int* __restrict__ dmask,
                                               const float* __restrict__ w_aggr, float* __restrict__ out) {
    __shared__ float xs[A_][C_];
    __shared__ float am[A_];
    int tt = blockIdx.x;
    int t = threadIdx.x;
    for (int e = t; e < A_*C_; e += 384) {
        int a = e >> 7, c = e & 127;
        int idx = q2a_idx[tt*A_ + a];
        int gm  = q2a_mask[tt*A_ + a];
        xs[a][c] = gm ? x[(size_t)idx*C_ + c] : 0.f;
    }
    if (t < A_) am[t] = (float)dmask[tt*A_ + t];
    __syncthreads();
    float acc[A_];
    #pragma unroll
    for (int a = 0; a < A_; a++) acc[a] = 0.f;
    for (int c = 0; c < C_; c++) {
        float wv = w_aggr[c*PTC_ + t];
        #pragma unroll
        for (int a = 0; a < A_; a++) acc[a] += xs[a][c] * wv;
    }
    float denom = 1e-10f, num = 0.f;
    #pragma unroll
    for (int a = 0; a < A_; a++) { denom += am[a]; num += am[a] * fmaxf(acc[a], 0.f); }
    out[(size_t)tt*PTC_ + t] = num / denom;
}

extern "C" void kernel_launch(void* const* d_in, const int* in_sizes, int n_in,
                              void* d_out, int out_size, void* d_ws, size_t ws_size,
                              hipStream_t stream) {
    const int*   qmask    = (const int*)d_in[0];
    const int*   dmask    = (const int*)d_in[1];
    const int*   a2q_idx  = (const int*)d_in[2];
    const int*   a2q_mask = (const int*)d_in[3];
    const int*   q2k_idx  = (const int*)d_in[4];
    const int*   q2k_mask = (const int*)d_in[5];
    const int*   q2a_idx  = (const int*)d_in[6];
    const int*   q2a_mask = (const int*)d_in[7];
    const float* ta_act   = (const float*)d_in[8];
    const float* qsc      = (const float*)d_in[9];
    const float* pair     = (const float*)d_in[10];
    const int*   kmask    = (const int*)d_in[11];
    const float* ksc      = (const float*)d_in[12];
    const float* w_pos    = (const float*)d_in[13];
    const float* w_aggr   = (const float*)d_in[14];
    const float* ln1_s    = (const float*)d_in[15];
    const float* ln1_b    = (const float*)d_in[16];
    const float* wq       = (const float*)d_in[17];
    const float* wk       = (const float*)d_in[18];
    const float* wv       = (const float*)d_in[19];
    const float* wpair    = (const float*)d_in[20];
    const float* wo       = (const float*)d_in[21];
    const float* ln2_s    = (const float*)d_in[22];
    const float* ln2_b    = (const float*)d_in[23];
    const float* w1       = (const float*)d_in[24];
    const float* w2       = (const float*)d_in[25];
    float* out = (float*)d_out;

    float* ws = (float*)d_ws;
    float*    x      = ws;                                     // SQ*C f32
    float*    xn     = x + (size_t)SQ_*C_;                     // SQ*C f32
    ushort_t* qb16   = (ushort_t*)(xn + (size_t)SQ_*C_);       // SQ*C bf16
    ushort_t* kb16   = qb16 + (size_t)SQ_*C_;                  // S*H*K*DH bf16
    ushort_t* vT16   = kb16 + (size_t)S_*H_*K_*DH_;            // S*H*DH*K bf16
    ushort_t* bias16 = vT16 + (size_t)S_*H_*K_*DH_;            // L*S*H*Q*K bf16 (56.6 MB)
    ushort_t* woT16  = bias16 + (size_t)L_*S_*H_*Q_*K_;        // L*C*C bf16
    float*    ffh    = (float*)kb16;                           // alias (dead after attn)

    k_init_x<<<(SQ_*C_)/256, 256, 0, stream>>>(a2q_idx, a2q_mask, qmask, ta_act, qsc, w_pos, x);
    k_bias<<<S_*16, 256, 0, stream>>>(pair, wpair, bias16);
    k_woT<<<(L_*C_*C_)/256, 256, 0, stream>>>(wo, woT16);

    for (int l = 0; l < L_; l++) {
        k_ln<<<SQ_, 128, 0, stream>>>(x, ln1_s + l*C_, ln1_b + l*C_, xn);
        k_qproj_m<<<SQ_/64, 256, 0, stream>>>(xn, wq + (size_t)l*C_*C_, qb16);
        k_kv_m<<<576, 256, 0, stream>>>(xn, q2k_idx, q2k_mask, ksc,
                                        wk + (size_t)l*C_*C_, wv + (size_t)l*C_*C_, kb16, vT16);
        k_attn_m<<<S_, 256, 0, stream>>>(qb16, kb16, vT16,
                                         bias16 + (size_t)l*S_*H_*Q_*K_, kmask,
                                         woT16 + (size_t)l*C_*C_, x);
        k_ln<<<SQ_, 128, 0, stream>>>(x, ln2_s + l*C_, ln2_b + l*C_, xn);
        k_ff1_m<<<SQ_/64, 256, 0, stream>>>(xn, w1 + (size_t)l*C_*FF_, ffh);
        k_ff2_m<<<SQ_/32, 256, 0, stream>>>(ffh, w2 + (size_t)l*FF_*C_, x);
    }

    k_finalmask<<<(SQ_*C_)/256, 256, 0, stream>>>(x, qmask, out + (size_t)T_*PTC_);
    k_token<<<T_, 384, 0, stream>>>(x, q2a_idx, q2a_mask, dmask, w_aggr, out);
}

// Round 7
// 503.263 us; speedup vs baseline: 7.6960x; 1.3328x over previous
//
#include <hip/hip_runtime.h>
#include <hip/hip_bf16.h>

#define T_ 768
#define A_ 24
#define S_ 576
#define Q_ 32
#define K_ 128
#define C_ 128
#define H_ 4
#define DH_ 32
#define L_ 3
#define PAIR_ 16
#define PTC_ 384
#define FF_ 256
#define SQ_ (S_*Q_)
#define SK_ (S_*K_)

typedef __attribute__((ext_vector_type(8))) short bf16x8;
typedef __attribute__((ext_vector_type(4))) float f32x4;
typedef unsigned short ushort_t;

#define MFMA(a,b,c) __builtin_amdgcn_mfma_f32_16x16x32_bf16(a,b,c,0,0,0)

__device__ inline unsigned short f2b(float f) {
    union { float f; unsigned u; } v; v.f = f;
    unsigned u = v.u;
    return (unsigned short)((u + 0x7FFFu + ((u >> 16) & 1u)) >> 16);
}
__device__ inline float b2f(unsigned short b) {
    union { unsigned u; float f; } v; v.u = ((unsigned)b) << 16;
    return v.f;
}

// load one MFMA fragment (8 bf16 along k) from swizzled LDS tile with row-length KD
template<int KD>
__device__ inline bf16x8 ldfrag(const unsigned short* lds, int row, int k) {
    int byte = ((row*KD + k)*2) ^ ((row & 7) << 4);
    return *(const bf16x8*)((const char*)lds + byte);
}

// ---------------- init: x = (gather(token_atoms) @ w_pos) * qm + qsc ----------------
__global__ void k_init_x(const int* __restrict__ a2q_idx, const int* __restrict__ a2q_mask,
                         const int* __restrict__ qmask, const float* __restrict__ ta_act,
                         const float* __restrict__ qsc, const float* __restrict__ w_pos,
                         float* __restrict__ x) {
    int i = blockIdx.x * blockDim.x + threadIdx.x;   // over SQ_*C_
    if (i >= SQ_ * C_) return;
    int r = i / C_, c = i % C_;
    float v = 0.f;
    if (a2q_mask[r]) {
        int idx = a2q_idx[r];
        float p0 = ta_act[idx*3+0], p1 = ta_act[idx*3+1], p2 = ta_act[idx*3+2];
        v = p0 * w_pos[c] + p1 * w_pos[C_+c] + p2 * w_pos[2*C_+c];
    }
    v *= (float)qmask[r];
    x[i] = v + qsc[i];
}

// ---------------- LayerNorm -> bf16 output ----------------
__global__ void k_ln(const float* __restrict__ x, const float* __restrict__ s,
                     const float* __restrict__ b, ushort_t* __restrict__ xn16) {
    int r = blockIdx.x;
    int c = threadIdx.x;
    __shared__ float red[C_];
    float v = x[(size_t)r*C_ + c];
    red[c] = v; __syncthreads();
    for (int off = 64; off > 0; off >>= 1) { if (c < off) red[c] += red[c+off]; __syncthreads(); }
    float mean = red[0] * (1.0f/C_);
    __syncthreads();
    float d = v - mean;
    red[c] = d*d; __syncthreads();
    for (int off = 64; off > 0; off >>= 1) { if (c < off) red[c] += red[c+off]; __syncthreads(); }
    float var = red[0] * (1.0f/C_);
    xn16[(size_t)r*C_ + c] = f2b(d * rsqrtf(var + 1e-5f) * s[c] + b[c]);
}

// ---------------- pair-bias precompute: bias16[l][s][h][qq][kk] = pair . wpair ----------------
__global__ __launch_bounds__(256) void k_bias(const float* __restrict__ pair,
                                              const float* __restrict__ wpair,
                                              ushort_t* __restrict__ bias16) {
    int s  = blockIdx.x >> 4;
    int qq = (blockIdx.x & 15)*2 + (threadIdx.x >> 7);
    int kk = threadIdx.x & 127;
    const float4* pp = (const float4*)(pair + (((size_t)s*Q_ + qq)*K_ + kk)*PAIR_);
    float4 p0 = pp[0], p1 = pp[1], p2 = pp[2], p3 = pp[3];
    float pv[PAIR_] = {p0.x,p0.y,p0.z,p0.w, p1.x,p1.y,p1.z,p1.w,
                       p2.x,p2.y,p2.z,p2.w, p3.x,p3.y,p3.z,p3.w};
    #pragma unroll
    for (int l = 0; l < L_; l++)
    #pragma unroll
    for (int h = 0; h < H_; h++) {
        float acc = 0.f;
        #pragma unroll
        for (int p = 0; p < PAIR_; p++) acc += pv[p] * wpair[l*PAIR_*H_ + p*H_ + h];
        bias16[(((size_t)l*S_ + s)*H_ + h)*(Q_*K_) + qq*K_ + kk] = f2b(acc);
    }
}

// ---------------- weight prep: all GEMM weights -> bf16 transposed [l][n][k] ----------------
__device__ inline void wtr(const float* __restrict__ src, ushort_t* __restrict__ dst,
                           int e, int KD, int ND) {
    int l = e / (KD*ND), r = e % (KD*ND);
    int n = r / KD, k = r % KD;
    dst[e] = f2b(src[(size_t)l*KD*ND + (size_t)k*ND + n]);
}
__global__ void k_wprep(const float* __restrict__ wq, const float* __restrict__ wk,
                        const float* __restrict__ wv, const float* __restrict__ w1,
                        const float* __restrict__ w2, const float* __restrict__ wo,
                        ushort_t* __restrict__ wqT, ushort_t* __restrict__ wkT,
                        ushort_t* __restrict__ wvT, ushort_t* __restrict__ w1T,
                        ushort_t* __restrict__ w2T, ushort_t* __restrict__ woT) {
    int e = blockIdx.x * 256 + threadIdx.x;
    const int s_cc = L_*C_*C_;    // 49152
    const int s_cf = L_*C_*FF_;   // 98304
    if (e < s_cc)                 { wtr(wq, wqT, e, C_, C_); return; }
    e -= s_cc;
    if (e < s_cc)                 { wtr(wk, wkT, e, C_, C_); return; }
    e -= s_cc;
    if (e < s_cc)                 { wtr(wv, wvT, e, C_, C_); return; }
    e -= s_cc;
    if (e < s_cf)                 { wtr(w1, w1T, e, C_, FF_); return; }
    e -= s_cf;
    if (e < s_cf)                 { wtr(w2, w2T, e, FF_, C_); return; }
    e -= s_cf;
    if (e < s_cc)                 { wtr(wo, woT, e, C_, C_); return; }
}

// ---------------- q projection: no LDS, A/B frags direct from global bf16 ----------------
__global__ __launch_bounds__(256) void k_qproj_m(const ushort_t* __restrict__ xn16,
                                                 const ushort_t* __restrict__ wqT,
                                                 ushort_t* __restrict__ qb16) {
    int r0 = blockIdx.x * 64;
    int t = threadIdx.x, wid = t>>6, lane = t&63, lr = lane&15, g = lane>>4;
    int mh = (wid&1)*32, nh = (wid>>1)*64;
    f32x4 acc[2][4] = {};
    #pragma unroll
    for (int ks = 0; ks < 4; ks++) {
        int ka = ks*32 + g*8;
        bf16x8 a0 = *(const bf16x8*)(xn16 + (size_t)(r0 + mh + lr)*C_ + ka);
        bf16x8 a1 = *(const bf16x8*)(xn16 + (size_t)(r0 + mh + 16 + lr)*C_ + ka);
        #pragma unroll
        for (int nt = 0; nt < 4; nt++) {
            bf16x8 b = *(const bf16x8*)(wqT + (size_t)(nh + nt*16 + lr)*C_ + ka);
            acc[0][nt] = MFMA(a0, b, acc[0][nt]);
            acc[1][nt] = MFMA(a1, b, acc[1][nt]);
        }
    }
    const float scale = 0.17677669529663687f;  // 1/sqrt(32)
    #pragma unroll
    for (int mt = 0; mt < 2; mt++)
    #pragma unroll
    for (int nt = 0; nt < 4; nt++)
    #pragma unroll
    for (int r = 0; r < 4; r++) {
        int row = r0 + mh + mt*16 + g*4 + r;
        int col = nh + nt*16 + lr;
        int s = row>>5, qq = row&31, h = col>>5, dd = col&31;
        qb16[(((size_t)s*H_ + h)*Q_ + qq)*DH_ + dd] = f2b(acc[mt][nt][r] * scale);
    }
}

// ------- keys gather (16 KB LDS) + K/V projection; weights direct from global -------
__global__ __launch_bounds__(256) void k_kv_m(const ushort_t* __restrict__ xn16,
    const int* __restrict__ q2k_idx, const int* __restrict__ q2k_mask,
    const float* __restrict__ ksc,
    const ushort_t* __restrict__ wkT, const ushort_t* __restrict__ wvT,
    ushort_t* __restrict__ kb16, ushort_t* __restrict__ vT16) {
    __shared__ unsigned short at[64*C_];   // 16 KB, swizzled
    int t = threadIdx.x, wid = t>>6, lane = t&63, lr = lane&15, g = lane>>4;
    int r0 = blockIdx.x * 64;
    // gather + add ksc -> bf16 LDS (16-B stores)
    for (int e8 = t; e8 < 64*(C_/8); e8 += 256) {
        int row = e8 >> 4, c8 = (e8 & 15)*8;
        int gr = r0 + row;
        float vv[8];
        if (q2k_mask[gr]) {
            bf16x8 xv = *(const bf16x8*)(xn16 + (size_t)q2k_idx[gr]*C_ + c8);
            #pragma unroll
            for (int j = 0; j < 8; j++) vv[j] = b2f((unsigned short)xv[j]);
        } else {
            #pragma unroll
            for (int j = 0; j < 8; j++) vv[j] = 0.f;
        }
        const float4* kc = (const float4*)(ksc + (size_t)gr*C_ + c8);
        float4 k0 = kc[0], k1 = kc[1];
        vv[0]+=k0.x; vv[1]+=k0.y; vv[2]+=k0.z; vv[3]+=k0.w;
        vv[4]+=k1.x; vv[5]+=k1.y; vv[6]+=k1.z; vv[7]+=k1.w;
        bf16x8 o;
        #pragma unroll
        for (int j = 0; j < 8; j++) o[j] = (short)f2b(vv[j]);
        int byte = ((row*C_ + c8)*2) ^ ((row & 7) << 4);
        *(bf16x8*)((char*)at + byte) = o;
    }
    __syncthreads();
    int mh = (wid&1)*32, nh = (wid>>1)*64;
    f32x4 acc[2][4][2] = {};
    #pragma unroll
    for (int ks = 0; ks < 4; ks++) {
        int ka = ks*32 + g*8;
        bf16x8 a0 = ldfrag<C_>(at, mh + lr, ka);
        bf16x8 a1 = ldfrag<C_>(at, mh + 16 + lr, ka);
        #pragma unroll
        for (int nt = 0; nt < 4; nt++) {
            bf16x8 bk = *(const bf16x8*)(wkT + (size_t)(nh + nt*16 + lr)*C_ + ka);
            bf16x8 bv = *(const bf16x8*)(wvT + (size_t)(nh + nt*16 + lr)*C_ + ka);
            acc[0][nt][0] = MFMA(a0, bk, acc[0][nt][0]);
            acc[1][nt][0] = MFMA(a1, bk, acc[1][nt][0]);
            acc[0][nt][1] = MFMA(a0, bv, acc[0][nt][1]);
            acc[1][nt][1] = MFMA(a1, bv, acc[1][nt][1]);
        }
    }
    #pragma unroll
    for (int mt = 0; mt < 2; mt++)
    #pragma unroll
    for (int nt = 0; nt < 4; nt++)
    #pragma unroll
    for (int r = 0; r < 4; r++) {
        int row = r0 + mh + mt*16 + g*4 + r;
        int col = nh + nt*16 + lr;
        int s = row>>7, kk = row&127, h = col>>5, dd = col&31;
        kb16[(((size_t)s*H_ + h)*K_ + kk)*DH_ + dd] = f2b(acc[mt][nt][0][r]);
        vT16[(((size_t)s*H_ + h)*DH_ + dd)*K_ + kk] = f2b(acc[mt][nt][1][r]);
    }
}

// ---------------- MFMA attention: 1 subset/block, 1 head/wave; precomputed bias ----------------
__global__ __launch_bounds__(256) void k_attn_m(
    const ushort_t* __restrict__ qb16, const ushort_t* __restrict__ kb16,
    const ushort_t* __restrict__ vT16, const ushort_t* __restrict__ bias16,
    const int* __restrict__ kmask_g, const ushort_t* __restrict__ woT16,
    float* __restrict__ x) {
    __shared__ unsigned short BP[H_][Q_*K_];   // 32 KB: bias, then P (per-head plane)
    __shared__ unsigned short O_lds[Q_*C_];    // 8 KB, swizzled
    int s = blockIdx.x, t = threadIdx.x;
    int w = t>>6, lane = t&63, lr = lane&15, g = lane>>4;

    // stage bias -> LDS, swizzle byte ^= ((qq>>2)&3)<<5  (coalesced global reads)
    {
        const ushort_t* bb = bias16 + (size_t)s*H_*Q_*K_;
        for (int e8 = t; e8 < H_*Q_*K_/8; e8 += 256) {
            int h = e8 >> 9, rem = e8 & 511;
            int qq = rem >> 4, kk0 = (rem & 15)*8;
            bf16x8 v = *(const bf16x8*)(bb + h*(Q_*K_) + qq*K_ + kk0);
            int byte = ((qq*K_ + kk0)*2) ^ (((qq>>2)&3)<<5);
            *(bf16x8*)((char*)&BP[h][0] + byte) = v;
        }
    }

    // q fragments direct from global
    const ushort_t* qbase = qb16 + ((size_t)(s*H_ + w)*Q_)*DH_;
    bf16x8 aq0 = *(const bf16x8*)(qbase + (size_t)lr*DH_ + g*8);
    bf16x8 aq1 = *(const bf16x8*)(qbase + (size_t)(16+lr)*DH_ + g*8);

    // logits = q @ k^T  (16 MFMAs), k direct from global
    const ushort_t* kbase = kb16 + ((size_t)(s*H_ + w)*K_)*DH_;
    f32x4 acc[2][8] = {};
    #pragma unroll
    for (int nt = 0; nt < 8; nt++) {
        bf16x8 b = *(const bf16x8*)(kbase + (size_t)(nt*16+lr)*DH_ + g*8);
        acc[0][nt] = MFMA(aq0, b, acc[0][nt]);
        acc[1][nt] = MFMA(aq1, b, acc[1][nt]);
    }

    // key mask per nt (col = nt*16+lr)
    float km[8];
    #pragma unroll
    for (int nt = 0; nt < 8; nt++) km[nt] = (kmask_g[s*K_ + nt*16 + lr] - 1.0f) * 1e9f;

    __syncthreads();   // bias staged

    // bias add from own plane (D-fragment pattern)
    unsigned short* Pb = &BP[w][0];
    #pragma unroll
    for (int mt = 0; mt < 2; mt++)
    #pragma unroll
    for (int r = 0; r < 4; r++) {
        int qq = mt*16 + g*4 + r;
        #pragma unroll
        for (int nt = 0; nt < 8; nt++) {
            int byte = ((qq*K_ + nt*16 + lr)*2) ^ (((qq>>2)&3)<<5);
            acc[mt][nt][r] += b2f(*(unsigned short*)((char*)Pb + byte)) + km[nt];
        }
    }

    // in-register softmax over kk (16 lanes x 8 nt per row)
    float inv[2][4];
    #pragma unroll
    for (int mt = 0; mt < 2; mt++)
    #pragma unroll
    for (int r = 0; r < 4; r++) {
        float mx = acc[mt][0][r];
        #pragma unroll
        for (int nt = 1; nt < 8; nt++) mx = fmaxf(mx, acc[mt][nt][r]);
        #pragma unroll
        for (int m = 1; m <= 8; m <<= 1) mx = fmaxf(mx, __shfl_xor(mx, m));
        float sum = 0.f;
        #pragma unroll
        for (int nt = 0; nt < 8; nt++) {
            float e = __expf(acc[mt][nt][r] - mx);
            acc[mt][nt][r] = e;
            sum += e;
        }
        #pragma unroll
        for (int m = 1; m <= 8; m <<= 1) sum += __shfl_xor(sum, m);
        inv[mt][r] = 1.0f / sum;
    }

    // P -> own plane (bias fully consumed; same wave, no barrier needed)
    #pragma unroll
    for (int mt = 0; mt < 2; mt++)
    #pragma unroll
    for (int r = 0; r < 4; r++) {
        int row = mt*16 + g*4 + r;
        #pragma unroll
        for (int nt = 0; nt < 8; nt++) {
            int byte = ((row*K_ + nt*16 + lr)*2) ^ ((row & 7) << 4);
            *(unsigned short*)((char*)Pb + byte) = f2b(acc[mt][nt][r]);
        }
    }

    // PV: P(32x128) @ v^T-frags, v direct from global
    const ushort_t* vbase = vT16 + ((size_t)(s*H_ + w)*DH_)*K_;
    f32x4 po[2][2] = {};
    #pragma unroll
    for (int ks = 0; ks < 4; ks++) {
        int kk0 = ks*32 + g*8;
        bf16x8 a0 = ldfrag<K_>(Pb, lr, kk0);
        bf16x8 a1 = ldfrag<K_>(Pb, 16 + lr, kk0);
        #pragma unroll
        for (int nt = 0; nt < 2; nt++) {
            bf16x8 b = *(const bf16x8*)(vbase + (size_t)(nt*16+lr)*K_ + kk0);
            po[0][nt] = MFMA(a0, b, po[0][nt]);
            po[1][nt] = MFMA(a1, b, po[1][nt]);
        }
    }

    // O -> LDS (normalize by 1/sum here)
    #pragma unroll
    for (int mt = 0; mt < 2; mt++)
    #pragma unroll
    for (int nt = 0; nt < 2; nt++)
    #pragma unroll
    for (int r = 0; r < 4; r++) {
        int row = mt*16 + g*4 + r;
        int col = w*32 + nt*16 + lr;
        int byte = ((row*C_ + col)*2) ^ ((row & 7) << 4);
        *(unsigned short*)((char*)O_lds + byte) = f2b(po[mt][nt][r] * inv[mt][r]);
    }
    __syncthreads();

    // output projection: wave w -> cols w*32..w*32+31; wo frags direct from global woT16
    f32x4 fo[2][2] = {};
    #pragma unroll
    for (int ks = 0; ks < 4; ks++) {
        int k0 = ks*32 + g*8;
        bf16x8 a0 = ldfrag<C_>(O_lds, lr, k0);
        bf16x8 a1 = ldfrag<C_>(O_lds, 16 + lr, k0);
        #pragma unroll
        for (int nt = 0; nt < 2; nt++) {
            bf16x8 b = *(const bf16x8*)(woT16 + (size_t)(w*32 + nt*16 + lr)*C_ + k0);
            fo[0][nt] = MFMA(a0, b, fo[0][nt]);
            fo[1][nt] = MFMA(a1, b, fo[1][nt]);
        }
    }
    #pragma unroll
    for (int mt = 0; mt < 2; mt++)
    #pragma unroll
    for (int nt = 0; nt < 2; nt++)
    #pragma unroll
    for (int r = 0; r < 4; r++) {
        int row = mt*16 + g*4 + r;
        int col = w*32 + nt*16 + lr;
        x[((size_t)s*Q_ + row)*C_ + col] += fo[mt][nt][r];
    }
}

// ---------------- FF1: ffh16 = relu(xn2 @ w1), no LDS ----------------
__global__ __launch_bounds__(256) void k_ff1_m(const ushort_t* __restrict__ xn16,
                                               const ushort_t* __restrict__ w1T,
                                               ushort_t* __restrict__ ffh16) {
    int r0 = blockIdx.x * 64;
    int t = threadIdx.x, wid = t>>6, lane = t&63, lr = lane&15, g = lane>>4;
    int mh = (wid&1)*32, nh = (wid>>1)*128;
    f32x4 acc[2][8] = {};
    #pragma unroll
    for (int ks = 0; ks < 4; ks++) {
        int ka = ks*32 + g*8;
        bf16x8 a0 = *(const bf16x8*)(xn16 + (size_t)(r0 + mh + lr)*C_ + ka);
        bf16x8 a1 = *(const bf16x8*)(xn16 + (size_t)(r0 + mh + 16 + lr)*C_ + ka);
        #pragma unroll
        for (int nt = 0; nt < 8; nt++) {
            bf16x8 b = *(const bf16x8*)(w1T + (size_t)(nh + nt*16 + lr)*C_ + ka);
            acc[0][nt] = MFMA(a0, b, acc[0][nt]);
            acc[1][nt] = MFMA(a1, b, acc[1][nt]);
        }
    }
    #pragma unroll
    for (int mt = 0; mt < 2; mt++)
    #pragma unroll
    for (int nt = 0; nt < 8; nt++)
    #pragma unroll
    for (int r = 0; r < 4; r++) {
        int row = r0 + mh + mt*16 + g*4 + r;
        int col = nh + nt*16 + lr;
        ffh16[(size_t)row*FF_ + col] = f2b(fmaxf(acc[mt][nt][r], 0.f));
    }
}

// ---------------- FF2: x += ffh @ w2, no LDS ----------------
__global__ __launch_bounds__(256) void k_ff2_m(const ushort_t* __restrict__ ffh16,
                                               const ushort_t* __restrict__ w2T,
                                               float* __restrict__ x) {
    int r0 = blockIdx.x * 64;
    int t = threadIdx.x, wid = t>>6, lane = t&63, lr = lane&15, g = lane>>4;
    int mh = (wid&1)*32, nh = (wid>>1)*64;
    f32x4 acc[2][4] = {};
    #pragma unroll
    for (int ks = 0; ks < 8; ks++) {
        int ka = ks*32 + g*8;
        bf16x8 a0 = *(const bf16x8*)(ffh16 + (size_t)(r0 + mh + lr)*FF_ + ka);
        bf16x8 a1 = *(const bf16x8*)(ffh16 + (size_t)(r0 + mh + 16 + lr)*FF_ + ka);
        #pragma unroll
        for (int nt = 0; nt < 4; nt++) {
            bf16x8 b = *(const bf16x8*)(w2T + (size_t)(nh + nt*16 + lr)*FF_ + ka);
            acc[0][nt] = MFMA(a0, b, acc[0][nt]);
            acc[1][nt] = MFMA(a1, b, acc[1][nt]);
        }
    }
    #pragma unroll
    for (int mt = 0; mt < 2; mt++)
    #pragma unroll
    for (int nt = 0; nt < 4; nt++)
    #pragma unroll
    for (int r = 0; r < 4; r++) {
        int row = r0 + mh + mt*16 + g*4 + r;
        int col = nh + nt*16 + lr;
        x[(size_t)row*C_ + col] += acc[mt][nt][r];
    }
}

// ---------------- final mask + write skip (f32 out) ----------------
__global__ void k_finalmask(float* __restrict__ x, const int* __restrict__ qmask,
                            float* __restrict__ out_skip) {
    int i = blockIdx.x * blockDim.x + threadIdx.x;
    if (i >= SQ_*C_) return;
    float v = x[i] * (float)qmask[i / C_];
    x[i] = v;
    out_skip[i] = v;
}

// ---------------- token aggregation (f32 out) ----------------
__global__ __launch_bounds__(384) void k_token(const float* __restrict__ x, const int* __restrict__ q2a_idx,
                                               const int* __restrict__ q2a_mask, const int* __restrict__ dmask,
                                               const float* __restrict__ w_aggr, float* __restrict__ out) {
    __shared__ float xs[A_][C_];
    __shared__ float am[A_];
    int tt = blockIdx.x;
    int t = threadIdx.x;
    for (int e = t; e < A_*C_; e += 384) {
        int a = e >> 7, c = e & 127;
        int idx = q2a_idx[tt*A_ + a];
        int gm  = q2a_mask[tt*A_ + a];
        xs[a][c] = gm ? x[(size_t)idx*C_ + c] : 0.f;
    }
    if (t < A_) am[t] = (float)dmask[tt*A_ + t];
    __syncthreads();
    float acc[A_];
    #pragma unroll
    for (int a = 0; a < A_; a++) acc[a] = 0.f;
    for (int c = 0; c < C_; c++) {
        float wv = w_aggr[c*PTC_ + t];
        #pragma unroll
        for (int a = 0; a < A_; a++) acc[a] += xs[a][c] * wv;
    }
    float denom = 1e-10f, num = 0.f;
    #pragma unroll
    for (int a = 0; a < A_; a++) { denom += am[a]; num += am[a] * fmaxf(acc[a], 0.f); }
    out[(size_t)tt*PTC_ + t] = num / denom;
}

extern "C" void kernel_launch(void* const* d_in, const int* in_sizes, int n_in,
                              void* d_out, int out_size, void* d_ws, size_t ws_size,
                              hipStream_t stream) {
    const int*   qmask    = (const int*)d_in[0];
    const int*   dmask    = (const int*)d_in[1];
    const int*   a2q_idx  = (const int*)d_in[2];
    const int*   a2q_mask = (const int*)d_in[3];
    const int*   q2k_idx  = (const int*)d_in[4];
    const int*   q2k_mask = (const int*)d_in[5];
    const int*   q2a_idx  = (const int*)d_in[6];
    const int*   q2a_mask = (const int*)d_in[7];
    const float* ta_act   = (const float*)d_in[8];
    const float* qsc      = (const float*)d_in[9];
    const float* pair     = (const float*)d_in[10];
    const int*   kmask    = (const int*)d_in[11];
    const float* ksc      = (const float*)d_in[12];
    const float* w_pos    = (const float*)d_in[13];
    const float* w_aggr   = (const float*)d_in[14];
    const float* ln1_s    = (const float*)d_in[15];
    const float* ln1_b    = (const float*)d_in[16];
    const float* wq       = (const float*)d_in[17];
    const float* wk       = (const float*)d_in[18];
    const float* wv       = (const float*)d_in[19];
    const float* wpair    = (const float*)d_in[20];
    const float* wo       = (const float*)d_in[21];
    const float* ln2_s    = (const float*)d_in[22];
    const float* ln2_b    = (const float*)d_in[23];
    const float* w1       = (const float*)d_in[24];
    const float* w2       = (const float*)d_in[25];
    float* out = (float*)d_out;

    float* ws = (float*)d_ws;
    float*    x      = ws;                                     // SQ*C f32
    ushort_t* xn16   = (ushort_t*)(x + (size_t)SQ_*C_);        // SQ*C bf16
    ushort_t* qb16   = xn16 + (size_t)SQ_*C_;                  // SQ*C bf16
    ushort_t* kb16   = qb16 + (size_t)SQ_*C_;                  // S*H*K*DH bf16
    ushort_t* vT16   = kb16 + (size_t)S_*H_*K_*DH_;            // S*H*DH*K bf16
    ushort_t* bias16 = vT16 + (size_t)S_*H_*K_*DH_;            // L*S*H*Q*K bf16
    ushort_t* woT16  = bias16 + (size_t)L_*S_*H_*Q_*K_;        // L*C*C
    ushort_t* wqT16  = woT16 + (size_t)L_*C_*C_;               // L*C*C
    ushort_t* wkT16  = wqT16 + (size_t)L_*C_*C_;               // L*C*C
    ushort_t* wvT16  = wkT16 + (size_t)L_*C_*C_;               // L*C*C
    ushort_t* w1T16  = wvT16 + (size_t)L_*C_*C_;               // L*C*FF
    ushort_t* w2T16  = w1T16 + (size_t)L_*C_*FF_;              // L*FF*C
    ushort_t* ffh16  = kb16;  // alias: used between ff1 and ff2 (kb16 dead there)

    k_init_x<<<(SQ_*C_)/256, 256, 0, stream>>>(a2q_idx, a2q_mask, qmask, ta_act, qsc, w_pos, x);
    k_bias<<<S_*16, 256, 0, stream>>>(pair, wpair, bias16);
    k_wprep<<<(4*L_*C_*C_ + 2*L_*C_*FF_)/256, 256, 0, stream>>>(wq, wk, wv, w1, w2, wo,
                                                                wqT16, wkT16, wvT16, w1T16, w2T16, woT16);

    for (int l = 0; l < L_; l++) {
        k_ln<<<SQ_, 128, 0, stream>>>(x, ln1_s + l*C_, ln1_b + l*C_, xn16);
        k_qproj_m<<<SQ_/64, 256, 0, stream>>>(xn16, wqT16 + (size_t)l*C_*C_, qb16);
        k_kv_m<<<SK_/64, 256, 0, stream>>>(xn16, q2k_idx, q2k_mask, ksc,
                                           wkT16 + (size_t)l*C_*C_, wvT16 + (size_t)l*C_*C_,
                                           kb16, vT16);
        k_attn_m<<<S_, 256, 0, stream>>>(qb16, kb16, vT16,
                                         bias16 + (size_t)l*S_*H_*Q_*K_, kmask,
                                         woT16 + (size_t)l*C_*C_, x);
        k_ln<<<SQ_, 128, 0, stream>>>(x, ln2_s + l*C_, ln2_b + l*C_, xn16);
        k_ff1_m<<<SQ_/64, 256, 0, stream>>>(xn16, w1T16 + (size_t)l*C_*FF_, ffh16);
        k_ff2_m<<<SQ_/64, 256, 0, stream>>>(ffh16, w2T16 + (size_t)l*FF_*C_, x);
    }

    k_finalmask<<<(SQ_*C_)/256, 256, 0, stream>>>(x, qmask, out + (size_t)T_*PTC_);
    k_token<<<T_, 384, 0, stream>>>(x, q2a_idx, q2a_mask, dmask, w_aggr, out);
}

// Round 8
// 444.961 us; speedup vs baseline: 8.7044x; 1.1310x over previous
//
#include <hip/hip_runtime.h>
#include <hip/hip_bf16.h>

#define T_ 768
#define A_ 24
#define S_ 576
#define Q_ 32
#define K_ 128
#define C_ 128
#define H_ 4
#define DH_ 32
#define L_ 3
#define PAIR_ 16
#define PTC_ 384
#define FF_ 256
#define SQ_ (S_*Q_)
#define SK_ (S_*K_)

typedef __attribute__((ext_vector_type(8))) short bf16x8;
typedef __attribute__((ext_vector_type(4))) short bf16x4;
typedef __attribute__((ext_vector_type(4))) float f32x4;
typedef unsigned short ushort_t;

#define MFMA(a,b,c) __builtin_amdgcn_mfma_f32_16x16x32_bf16(a,b,c,0,0,0)

__device__ inline unsigned short f2b(float f) {
    union { float f; unsigned u; } v; v.f = f;
    unsigned u = v.u;
    return (unsigned short)((u + 0x7FFFu + ((u >> 16) & 1u)) >> 16);
}
__device__ inline float b2f(unsigned short b) {
    union { unsigned u; float f; } v; v.u = ((unsigned)b) << 16;
    return v.f;
}

// load one MFMA fragment (8 bf16 along k) from swizzled LDS tile with row-length KD
template<int KD>
__device__ inline bf16x8 ldfrag(const unsigned short* lds, int row, int k) {
    int byte = ((row*KD + k)*2) ^ ((row & 7) << 4);
    return *(const bf16x8*)((const char*)lds + byte);
}

// ---- LN over 64 rows (4 threads/row), result -> swizzled LDS tile (+optional global bf16) ----
__device__ inline void ln_rows64(const float* __restrict__ x, size_t r0,
                                 const float* __restrict__ s, const float* __restrict__ b,
                                 unsigned short* at, ushort_t* __restrict__ xn16_opt) {
    int t = threadIdx.x;
    int row = t >> 2, q = t & 3;
    size_t gr = r0 + row;
    float v[32];
    const float4* xp = (const float4*)(x + gr*C_ + q*32);
    #pragma unroll
    for (int i = 0; i < 8; i++) {
        float4 f = xp[i];
        v[i*4]=f.x; v[i*4+1]=f.y; v[i*4+2]=f.z; v[i*4+3]=f.w;
    }
    float sum = 0.f;
    #pragma unroll
    for (int i = 0; i < 32; i++) sum += v[i];
    sum += __shfl_xor(sum, 1); sum += __shfl_xor(sum, 2);
    float mean = sum * (1.0f/C_);
    float sq = 0.f;
    #pragma unroll
    for (int i = 0; i < 32; i++) { float d = v[i]-mean; sq += d*d; }
    sq += __shfl_xor(sq, 1); sq += __shfl_xor(sq, 2);
    float rs = rsqrtf(sq * (1.0f/C_) + 1e-5f);
    #pragma unroll
    for (int i8 = 0; i8 < 4; i8++) {
        int c0 = q*32 + i8*8;
        const float4* sp = (const float4*)(s + c0);
        const float4* bp = (const float4*)(b + c0);
        float4 s0 = sp[0], s1 = sp[1], b0 = bp[0], b1 = bp[1];
        bf16x8 o;
        o[0] = (short)f2b((v[i8*8+0]-mean)*rs*s0.x + b0.x);
        o[1] = (short)f2b((v[i8*8+1]-mean)*rs*s0.y + b0.y);
        o[2] = (short)f2b((v[i8*8+2]-mean)*rs*s0.z + b0.z);
        o[3] = (short)f2b((v[i8*8+3]-mean)*rs*s0.w + b0.w);
        o[4] = (short)f2b((v[i8*8+4]-mean)*rs*s1.x + b1.x);
        o[5] = (short)f2b((v[i8*8+5]-mean)*rs*s1.y + b1.y);
        o[6] = (short)f2b((v[i8*8+6]-mean)*rs*s1.z + b1.z);
        o[7] = (short)f2b((v[i8*8+7]-mean)*rs*s1.w + b1.w);
        int byte = ((row*C_ + c0)*2) ^ ((row & 7) << 4);
        *(bf16x8*)((char*)at + byte) = o;
        if (xn16_opt) *(bf16x8*)(xn16_opt + gr*C_ + c0) = o;
    }
}

// ---------------- weight transpose helper ----------------
__device__ inline void wtr(const float* __restrict__ src, ushort_t* __restrict__ dst,
                           int e, int KD, int ND) {
    int l = e / (KD*ND), r = e % (KD*ND);
    int n = r / KD, k = r % KD;
    dst[e] = f2b(src[(size_t)l*KD*ND + (size_t)k*ND + n]);
}

#define NB_BIAS  (S_*16)
#define NB_WPREP ((4*L_*C_*C_ + 2*L_*C_*FF_)/256)
#define NB_INIT  ((SQ_*C_)/256)
#define NB_KSC   ((SK_*C_)/1024)

// ---------------- fused prep: bias16 | weight transposes | init x | ksc->bf16 ----------------
__global__ __launch_bounds__(256) void k_prep(
    const float* __restrict__ pair, const float* __restrict__ wpair, ushort_t* __restrict__ bias16,
    const float* __restrict__ wq, const float* __restrict__ wk, const float* __restrict__ wv,
    const float* __restrict__ w1, const float* __restrict__ w2, const float* __restrict__ wo,
    ushort_t* __restrict__ wqT, ushort_t* __restrict__ wkT, ushort_t* __restrict__ wvT,
    ushort_t* __restrict__ w1T, ushort_t* __restrict__ w2T, ushort_t* __restrict__ woT,
    const int* __restrict__ a2q_idx, const int* __restrict__ a2q_mask,
    const int* __restrict__ qmask, const float* __restrict__ ta_act,
    const float* __restrict__ qsc, const float* __restrict__ w_pos, float* __restrict__ x,
    const float* __restrict__ ksc, ushort_t* __restrict__ ksc16) {
    int blk = blockIdx.x, t = threadIdx.x;
    if (blk < NB_BIAS) {
        int s  = blk >> 4;
        int qq = (blk & 15)*2 + (t >> 7);
        int kk = t & 127;
        const float4* pp = (const float4*)(pair + (((size_t)s*Q_ + qq)*K_ + kk)*PAIR_);
        float4 p0 = pp[0], p1 = pp[1], p2 = pp[2], p3 = pp[3];
        float pv[PAIR_] = {p0.x,p0.y,p0.z,p0.w, p1.x,p1.y,p1.z,p1.w,
                           p2.x,p2.y,p2.z,p2.w, p3.x,p3.y,p3.z,p3.w};
        #pragma unroll
        for (int l = 0; l < L_; l++)
        #pragma unroll
        for (int h = 0; h < H_; h++) {
            float acc = 0.f;
            #pragma unroll
            for (int p = 0; p < PAIR_; p++) acc += pv[p] * wpair[l*PAIR_*H_ + p*H_ + h];
            bias16[(((size_t)l*S_ + s)*H_ + h)*(Q_*K_) + qq*K_ + kk] = f2b(acc);
        }
        return;
    }
    blk -= NB_BIAS;
    if (blk < NB_WPREP) {
        int e = blk * 256 + t;
        const int s_cc = L_*C_*C_;
        const int s_cf = L_*C_*FF_;
        if (e < s_cc)      { wtr(wq, wqT, e, C_, C_); return; }
        e -= s_cc;
        if (e < s_cc)      { wtr(wk, wkT, e, C_, C_); return; }
        e -= s_cc;
        if (e < s_cc)      { wtr(wv, wvT, e, C_, C_); return; }
        e -= s_cc;
        if (e < s_cf)      { wtr(w1, w1T, e, C_, FF_); return; }
        e -= s_cf;
        if (e < s_cf)      { wtr(w2, w2T, e, FF_, C_); return; }
        e -= s_cf;
        wtr(wo, woT, e, C_, C_);
        return;
    }
    blk -= NB_WPREP;
    if (blk < NB_INIT) {
        int i = blk * 256 + t;
        int r = i / C_, c = i % C_;
        float v = 0.f;
        if (a2q_mask[r]) {
            int idx = a2q_idx[r];
            float p0 = ta_act[idx*3+0], p1 = ta_act[idx*3+1], p2 = ta_act[idx*3+2];
            v = p0 * w_pos[c] + p1 * w_pos[C_+c] + p2 * w_pos[2*C_+c];
        }
        v *= (float)qmask[r];
        x[i] = v + qsc[i];
        return;
    }
    blk -= NB_INIT;
    {
        int e4 = blk * 256 + t;
        float4 f = ((const float4*)ksc)[e4];
        bf16x4 o;
        o[0] = (short)f2b(f.x); o[1] = (short)f2b(f.y);
        o[2] = (short)f2b(f.z); o[3] = (short)f2b(f.w);
        *(bf16x4*)(ksc16 + (size_t)e4*4) = o;
    }
}

// ---------------- LN1 + q projection fused ----------------
__global__ __launch_bounds__(256) void k_lnqproj(const float* __restrict__ x,
                                                 const float* __restrict__ s, const float* __restrict__ b,
                                                 const ushort_t* __restrict__ wqT,
                                                 ushort_t* __restrict__ xn16,
                                                 ushort_t* __restrict__ qb16) {
    __shared__ unsigned short at[64*C_];   // 16 KB
    size_t r0 = (size_t)blockIdx.x * 64;
    ln_rows64(x, r0, s, b, at, xn16);
    __syncthreads();
    int t = threadIdx.x, wid = t>>6, lane = t&63, lr = lane&15, g = lane>>4;
    int mh = (wid&1)*32, nh = (wid>>1)*64;
    f32x4 acc[2][4] = {};
    #pragma unroll
    for (int ks = 0; ks < 4; ks++) {
        int ka = ks*32 + g*8;
        bf16x8 a0 = ldfrag<C_>(at, mh + lr, ka);
        bf16x8 a1 = ldfrag<C_>(at, mh + 16 + lr, ka);
        #pragma unroll
        for (int nt = 0; nt < 4; nt++) {
            bf16x8 bb = *(const bf16x8*)(wqT + (size_t)(nh + nt*16 + lr)*C_ + ka);
            acc[0][nt] = MFMA(a0, bb, acc[0][nt]);
            acc[1][nt] = MFMA(a1, bb, acc[1][nt]);
        }
    }
    const float scale = 0.17677669529663687f;  // 1/sqrt(32)
    #pragma unroll
    for (int mt = 0; mt < 2; mt++)
    #pragma unroll
    for (int nt = 0; nt < 4; nt++)
    #pragma unroll
    for (int r = 0; r < 4; r++) {
        int row = (int)r0 + mh + mt*16 + g*4 + r;
        int col = nh + nt*16 + lr;
        int s2 = row>>5, qq = row&31, h = col>>5, dd = col&31;
        qb16[(((size_t)s2*H_ + h)*Q_ + qq)*DH_ + dd] = f2b(acc[mt][nt][r] * scale);
    }
}

// ------- keys gather (16 KB LDS) + K/V projection; weights direct from global -------
__global__ __launch_bounds__(256) void k_kv_m(const ushort_t* __restrict__ xn16,
    const int* __restrict__ q2k_idx, const int* __restrict__ q2k_mask,
    const ushort_t* __restrict__ ksc16,
    const ushort_t* __restrict__ wkT, const ushort_t* __restrict__ wvT,
    ushort_t* __restrict__ kb16, ushort_t* __restrict__ vT16) {
    __shared__ unsigned short at[64*C_];   // 16 KB, swizzled
    int t = threadIdx.x, wid = t>>6, lane = t&63, lr = lane&15, g = lane>>4;
    int r0 = blockIdx.x * 64;
    for (int e8 = t; e8 < 64*(C_/8); e8 += 256) {
        int row = e8 >> 4, c8 = (e8 & 15)*8;
        int gr = r0 + row;
        bf16x8 kc8 = *(const bf16x8*)(ksc16 + (size_t)gr*C_ + c8);
        bf16x8 o;
        if (q2k_mask[gr]) {
            bf16x8 xv = *(const bf16x8*)(xn16 + (size_t)q2k_idx[gr]*C_ + c8);
            #pragma unroll
            for (int j = 0; j < 8; j++)
                o[j] = (short)f2b(b2f((unsigned short)xv[j]) + b2f((unsigned short)kc8[j]));
        } else {
            o = kc8;
        }
        int byte = ((row*C_ + c8)*2) ^ ((row & 7) << 4);
        *(bf16x8*)((char*)at + byte) = o;
    }
    __syncthreads();
    int mh = (wid&1)*32, nh = (wid>>1)*64;
    f32x4 acc[2][4][2] = {};
    #pragma unroll
    for (int ks = 0; ks < 4; ks++) {
        int ka = ks*32 + g*8;
        bf16x8 a0 = ldfrag<C_>(at, mh + lr, ka);
        bf16x8 a1 = ldfrag<C_>(at, mh + 16 + lr, ka);
        #pragma unroll
        for (int nt = 0; nt < 4; nt++) {
            bf16x8 bk = *(const bf16x8*)(wkT + (size_t)(nh + nt*16 + lr)*C_ + ka);
            bf16x8 bv = *(const bf16x8*)(wvT + (size_t)(nh + nt*16 + lr)*C_ + ka);
            acc[0][nt][0] = MFMA(a0, bk, acc[0][nt][0]);
            acc[1][nt][0] = MFMA(a1, bk, acc[1][nt][0]);
            acc[0][nt][1] = MFMA(a0, bv, acc[0][nt][1]);
            acc[1][nt][1] = MFMA(a1, bv, acc[1][nt][1]);
        }
    }
    #pragma unroll
    for (int mt = 0; mt < 2; mt++)
    #pragma unroll
    for (int nt = 0; nt < 4; nt++)
    #pragma unroll
    for (int r = 0; r < 4; r++) {
        int row = r0 + mh + mt*16 + g*4 + r;
        int col = nh + nt*16 + lr;
        int s = row>>7, kk = row&127, h = col>>5, dd = col&31;
        kb16[(((size_t)s*H_ + h)*K_ + kk)*DH_ + dd] = f2b(acc[mt][nt][0][r]);
        vT16[(((size_t)s*H_ + h)*DH_ + dd)*K_ + kk] = f2b(acc[mt][nt][1][r]);
    }
}

// ---------------- MFMA attention: 1 subset/block, 1 head/wave; precomputed bias ----------------
__global__ __launch_bounds__(256) void k_attn_m(
    const ushort_t* __restrict__ qb16, const ushort_t* __restrict__ kb16,
    const ushort_t* __restrict__ vT16, const ushort_t* __restrict__ bias16,
    const int* __restrict__ kmask_g, const ushort_t* __restrict__ woT16,
    float* __restrict__ x) {
    __shared__ unsigned short BP[H_][Q_*K_];   // 32 KB: bias, then P (per-head plane)
    __shared__ unsigned short O_lds[Q_*C_];    // 8 KB, swizzled
    int s = blockIdx.x, t = threadIdx.x;
    int w = t>>6, lane = t&63, lr = lane&15, g = lane>>4;

    {
        const ushort_t* bb = bias16 + (size_t)s*H_*Q_*K_;
        for (int e8 = t; e8 < H_*Q_*K_/8; e8 += 256) {
            int h = e8 >> 9, rem = e8 & 511;
            int qq = rem >> 4, kk0 = (rem & 15)*8;
            bf16x8 v = *(const bf16x8*)(bb + h*(Q_*K_) + qq*K_ + kk0);
            int byte = ((qq*K_ + kk0)*2) ^ (((qq>>2)&3)<<5);
            *(bf16x8*)((char*)&BP[h][0] + byte) = v;
        }
    }

    const ushort_t* qbase = qb16 + ((size_t)(s*H_ + w)*Q_)*DH_;
    bf16x8 aq0 = *(const bf16x8*)(qbase + (size_t)lr*DH_ + g*8);
    bf16x8 aq1 = *(const bf16x8*)(qbase + (size_t)(16+lr)*DH_ + g*8);

    const ushort_t* kbase = kb16 + ((size_t)(s*H_ + w)*K_)*DH_;
    f32x4 acc[2][8] = {};
    #pragma unroll
    for (int nt = 0; nt < 8; nt++) {
        bf16x8 b = *(const bf16x8*)(kbase + (size_t)(nt*16+lr)*DH_ + g*8);
        acc[0][nt] = MFMA(aq0, b, acc[0][nt]);
        acc[1][nt] = MFMA(aq1, b, acc[1][nt]);
    }

    float km[8];
    #pragma unroll
    for (int nt = 0; nt < 8; nt++) km[nt] = (kmask_g[s*K_ + nt*16 + lr] - 1.0f) * 1e9f;

    __syncthreads();   // bias staged

    unsigned short* Pb = &BP[w][0];
    #pragma unroll
    for (int mt = 0; mt < 2; mt++)
    #pragma unroll
    for (int r = 0; r < 4; r++) {
        int qq = mt*16 + g*4 + r;
        #pragma unroll
        for (int nt = 0; nt < 8; nt++) {
            int byte = ((qq*K_ + nt*16 + lr)*2) ^ (((qq>>2)&3)<<5);
            acc[mt][nt][r] += b2f(*(unsigned short*)((char*)Pb + byte)) + km[nt];
        }
    }

    float inv[2][4];
    #pragma unroll
    for (int mt = 0; mt < 2; mt++)
    #pragma unroll
    for (int r = 0; r < 4; r++) {
        float mx = acc[mt][0][r];
        #pragma unroll
        for (int nt = 1; nt < 8; nt++) mx = fmaxf(mx, acc[mt][nt][r]);
        #pragma unroll
        for (int m = 1; m <= 8; m <<= 1) mx = fmaxf(mx, __shfl_xor(mx, m));
        float sum = 0.f;
        #pragma unroll
        for (int nt = 0; nt < 8; nt++) {
            float e = __expf(acc[mt][nt][r] - mx);
            acc[mt][nt][r] = e;
            sum += e;
        }
        #pragma unroll
        for (int m = 1; m <= 8; m <<= 1) sum += __shfl_xor(sum, m);
        inv[mt][r] = 1.0f / sum;
    }

    #pragma unroll
    for (int mt = 0; mt < 2; mt++)
    #pragma unroll
    for (int r = 0; r < 4; r++) {
        int row = mt*16 + g*4 + r;
        #pragma unroll
        for (int nt = 0; nt < 8; nt++) {
            int byte = ((row*K_ + nt*16 + lr)*2) ^ ((row & 7) << 4);
            *(unsigned short*)((char*)Pb + byte) = f2b(acc[mt][nt][r]);
        }
    }

    const ushort_t* vbase = vT16 + ((size_t)(s*H_ + w)*DH_)*K_;
    f32x4 po[2][2] = {};
    #pragma unroll
    for (int ks = 0; ks < 4; ks++) {
        int kk0 = ks*32 + g*8;
        bf16x8 a0 = ldfrag<K_>(Pb, lr, kk0);
        bf16x8 a1 = ldfrag<K_>(Pb, 16 + lr, kk0);
        #pragma unroll
        for (int nt = 0; nt < 2; nt++) {
            bf16x8 b = *(const bf16x8*)(vbase + (size_t)(nt*16+lr)*K_ + kk0);
            po[0][nt] = MFMA(a0, b, po[0][nt]);
            po[1][nt] = MFMA(a1, b, po[1][nt]);
        }
    }

    #pragma unroll
    for (int mt = 0; mt < 2; mt++)
    #pragma unroll
    for (int nt = 0; nt < 2; nt++)
    #pragma unroll
    for (int r = 0; r < 4; r++) {
        int row = mt*16 + g*4 + r;
        int col = w*32 + nt*16 + lr;
        int byte = ((row*C_ + col)*2) ^ ((row & 7) << 4);
        *(unsigned short*)((char*)O_lds + byte) = f2b(po[mt][nt][r] * inv[mt][r]);
    }
    __syncthreads();

    f32x4 fo[2][2] = {};
    #pragma unroll
    for (int ks = 0; ks < 4; ks++) {
        int k0 = ks*32 + g*8;
        bf16x8 a0 = ldfrag<C_>(O_lds, lr, k0);
        bf16x8 a1 = ldfrag<C_>(O_lds, 16 + lr, k0);
        #pragma unroll
        for (int nt = 0; nt < 2; nt++) {
            bf16x8 b = *(const bf16x8*)(woT16 + (size_t)(w*32 + nt*16 + lr)*C_ + k0);
            fo[0][nt] = MFMA(a0, b, fo[0][nt]);
            fo[1][nt] = MFMA(a1, b, fo[1][nt]);
        }
    }
    #pragma unroll
    for (int mt = 0; mt < 2; mt++)
    #pragma unroll
    for (int nt = 0; nt < 2; nt++)
    #pragma unroll
    for (int r = 0; r < 4; r++) {
        int row = mt*16 + g*4 + r;
        int col = w*32 + nt*16 + lr;
        x[((size_t)s*Q_ + row)*C_ + col] += fo[mt][nt][r];
    }
}

// ---------------- LN2 + FF1 + FF2 fused (ffh stays in LDS); optional final mask+skip ----------------
__global__ __launch_bounds__(256) void k_lnff(const float* __restrict__ x_in, float* __restrict__ x,
                                              const float* __restrict__ s, const float* __restrict__ b,
                                              const ushort_t* __restrict__ w1T,
                                              const ushort_t* __restrict__ w2T,
                                              const int* __restrict__ qmask_opt,
                                              float* __restrict__ skip_opt) {
    __shared__ unsigned short at[64*C_];    // 16 KB
    __shared__ unsigned short fft[64*FF_];  // 32 KB
    size_t r0 = (size_t)blockIdx.x * 64;
    ln_rows64(x_in, r0, s, b, at, nullptr);
    __syncthreads();
    int t = threadIdx.x, wid = t>>6, lane = t&63, lr = lane&15, g = lane>>4;
    // FF1: 64x256 = relu(at @ w1T)
    {
        int mh = (wid&1)*32, nh = (wid>>1)*128;
        f32x4 acc[2][8] = {};
        #pragma unroll
        for (int ks = 0; ks < 4; ks++) {
            int ka = ks*32 + g*8;
            bf16x8 a0 = ldfrag<C_>(at, mh + lr, ka);
            bf16x8 a1 = ldfrag<C_>(at, mh + 16 + lr, ka);
            #pragma unroll
            for (int nt = 0; nt < 8; nt++) {
                bf16x8 bb = *(const bf16x8*)(w1T + (size_t)(nh + nt*16 + lr)*C_ + ka);
                acc[0][nt] = MFMA(a0, bb, acc[0][nt]);
                acc[1][nt] = MFMA(a1, bb, acc[1][nt]);
            }
        }
        #pragma unroll
        for (int mt = 0; mt < 2; mt++)
        #pragma unroll
        for (int nt = 0; nt < 8; nt++)
        #pragma unroll
        for (int r = 0; r < 4; r++) {
            int row = mh + mt*16 + g*4 + r;
            int col = nh + nt*16 + lr;
            int byte = ((row*FF_ + col)*2) ^ ((row & 7) << 4);
            *(unsigned short*)((char*)fft + byte) = f2b(fmaxf(acc[mt][nt][r], 0.f));
        }
    }
    __syncthreads();
    // FF2: x += fft @ w2T
    {
        int mh = (wid&1)*32, nh = (wid>>1)*64;
        f32x4 acc[2][4] = {};
        #pragma unroll
        for (int ks = 0; ks < 8; ks++) {
            int ka = ks*32 + g*8;
            bf16x8 a0 = ldfrag<FF_>(fft, mh + lr, ka);
            bf16x8 a1 = ldfrag<FF_>(fft, mh + 16 + lr, ka);
            #pragma unroll
            for (int nt = 0; nt < 4; nt++) {
                bf16x8 bb = *(const bf16x8*)(w2T + (size_t)(nh + nt*16 + lr)*FF_ + ka);
                acc[0][nt] = MFMA(a0, bb, acc[0][nt]);
                acc[1][nt] = MFMA(a1, bb, acc[1][nt]);
            }
        }
        #pragma unroll
        for (int mt = 0; mt < 2; mt++)
        #pragma unroll
        for (int nt = 0; nt < 4; nt++)
        #pragma unroll
        for (int r = 0; r < 4; r++) {
            int row = (int)r0 + mh + mt*16 + g*4 + r;
            int col = nh + nt*16 + lr;
            size_t o = (size_t)row*C_ + col;
            float v = x[o] + acc[mt][nt][r];
            if (qmask_opt) {
                v *= (float)qmask_opt[row];
                skip_opt[o] = v;
            }
            x[o] = v;
        }
    }
}

// ---------------- token aggregation (f32 out) ----------------
__global__ __launch_bounds__(384) void k_token(const float* __restrict__ x, const int* __restrict__ q2a_idx,
                                               const int* __restrict__ q2a_mask, const int* __restrict__ dmask,
                                               const float* __restrict__ w_aggr, float* __restrict__ out) {
    __shared__ float xs[A_][C_];
    __shared__ float am[A_];
    int tt = blockIdx.x;
    int t = threadIdx.x;
    for (int e = t; e < A_*C_; e += 384) {
        int a = e >> 7, c = e & 127;
        int idx = q2a_idx[tt*A_ + a];
        int gm  = q2a_mask[tt*A_ + a];
        xs[a][c] = gm ? x[(size_t)idx*C_ + c] : 0.f;
    }
    if (t < A_) am[t] = (float)dmask[tt*A_ + t];
    __syncthreads();
    float acc[A_];
    #pragma unroll
    for (int a = 0; a < A_; a++) acc[a] = 0.f;
    for (int c = 0; c < C_; c++) {
        float wv = w_aggr[c*PTC_ + t];
        #pragma unroll
        for (int a = 0; a < A_; a++) acc[a] += xs[a][c] * wv;
    }
    float denom = 1e-10f, num = 0.f;
    #pragma unroll
    for (int a = 0; a < A_; a++) { denom += am[a]; num += am[a] * fmaxf(acc[a], 0.f); }
    out[(size_t)tt*PTC_ + t] = num / denom;
}

extern "C" void kernel_launch(void* const* d_in, const int* in_sizes, int n_in,
                              void* d_out, int out_size, void* d_ws, size_t ws_size,
                              hipStream_t stream) {
    const int*   qmask    = (const int*)d_in[0];
    const int*   dmask    = (const int*)d_in[1];
    const int*   a2q_idx  = (const int*)d_in[2];
    const int*   a2q_mask = (const int*)d_in[3];
    const int*   q2k_idx  = (const int*)d_in[4];
    const int*   q2k_mask = (const int*)d_in[5];
    const int*   q2a_idx  = (const int*)d_in[6];
    const int*   q2a_mask = (const int*)d_in[7];
    const float* ta_act   = (const float*)d_in[8];
    const float* qsc      = (const float*)d_in[9];
    const float* pair     = (const float*)d_in[10];
    const int*   kmask    = (const int*)d_in[11];
    const float* ksc      = (const float*)d_in[12];
    const float* w_pos    = (const float*)d_in[13];
    const float* w_aggr   = (const float*)d_in[14];
    const float* ln1_s    = (const float*)d_in[15];
    const float* ln1_b    = (const float*)d_in[16];
    const float* wq       = (const float*)d_in[17];
    const float* wk       = (const float*)d_in[18];
    const float* wv       = (const float*)d_in[19];
    const float* wpair    = (const float*)d_in[20];
    const float* wo       = (const float*)d_in[21];
    const float* ln2_s    = (const float*)d_in[22];
    const float* ln2_b    = (const float*)d_in[23];
    const float* w1       = (const float*)d_in[24];
    const float* w2       = (const float*)d_in[25];
    float* out = (float*)d_out;

    float* ws = (float*)d_ws;
    float*    x      = ws;                                     // SQ*C f32
    ushort_t* xn16   = (ushort_t*)(x + (size_t)SQ_*C_);        // SQ*C bf16
    ushort_t* qb16   = xn16 + (size_t)SQ_*C_;                  // SQ*C bf16
    ushort_t* kb16   = qb16 + (size_t)SQ_*C_;                  // S*H*K*DH bf16
    ushort_t* vT16   = kb16 + (size_t)S_*H_*K_*DH_;            // S*H*DH*K bf16
    ushort_t* bias16 = vT16 + (size_t)S_*H_*K_*DH_;            // L*S*H*Q*K bf16
    ushort_t* woT16  = bias16 + (size_t)L_*S_*H_*Q_*K_;        // L*C*C
    ushort_t* wqT16  = woT16 + (size_t)L_*C_*C_;               // L*C*C
    ushort_t* wkT16  = wqT16 + (size_t)L_*C_*C_;               // L*C*C
    ushort_t* wvT16  = wkT16 + (size_t)L_*C_*C_;               // L*C*C
    ushort_t* w1T16  = wvT16 + (size_t)L_*C_*C_;               // L*C*FF
    ushort_t* w2T16  = w1T16 + (size_t)L_*C_*FF_;              // L*FF*C
    ushort_t* ksc16  = w2T16 + (size_t)L_*FF_*C_;              // S*K*C bf16

    k_prep<<<NB_BIAS + NB_WPREP + NB_INIT + NB_KSC, 256, 0, stream>>>(
        pair, wpair, bias16,
        wq, wk, wv, w1, w2, wo, wqT16, wkT16, wvT16, w1T16, w2T16, woT16,
        a2q_idx, a2q_mask, qmask, ta_act, qsc, w_pos, x,
        ksc, ksc16);

    for (int l = 0; l < L_; l++) {
        k_lnqproj<<<SQ_/64, 256, 0, stream>>>(x, ln1_s + l*C_, ln1_b + l*C_,
                                              wqT16 + (size_t)l*C_*C_, xn16, qb16);
        k_kv_m<<<SK_/64, 256, 0, stream>>>(xn16, q2k_idx, q2k_mask, ksc16,
                                           wkT16 + (size_t)l*C_*C_, wvT16 + (size_t)l*C_*C_,
                                           kb16, vT16);
        k_attn_m<<<S_, 256, 0, stream>>>(qb16, kb16, vT16,
                                         bias16 + (size_t)l*S_*H_*Q_*K_, kmask,
                                         woT16 + (size_t)l*C_*C_, x);
        int last = (l == L_-1);
        k_lnff<<<SQ_/64, 256, 0, stream>>>(x, x, ln2_s + l*C_, ln2_b + l*C_,
                                           w1T16 + (size_t)l*C_*FF_, w2T16 + (size_t)l*FF_*C_,
                                           last ? qmask : nullptr,
                                           last ? (out + (size_t)T_*PTC_) : nullptr);
    }

    k_token<<<T_, 384, 0, stream>>>(x, q2a_idx, q2a_mask, dmask, w_aggr, out);
}